// Round 8
// baseline (3896.708 us; speedup 1.0000x reference)
//
#include <hip/hip_runtime.h>
#include <hip/hip_bf16.h>
#include <math.h>

// ---------------- constants ----------------
#define PI_F 3.14159265358979323846f
#define TWO_PI_F 6.283185307179586f

constexpr int BB = 4;            // batch
constexpr int FF_ = 2048;        // frames
constexpr int RC = 512;          // rnn channels
constexpr int HOP = 256;
constexpr int KK = 1024;         // FIR len
constexpr int LL = HOP + KK - 1; // 1279
constexpr size_t TOT = 525311;   // (F-1)*HOP + L
constexpr int APAD = 24064;      // zero pad in front of audio rows (>= REV-1, mult of 64)
constexpr size_t AROW = 549376;  // APAD + 525312
constexpr int REV = 24000;
constexpr size_t AROW2 = 551424; // af16 row halves: AROW + 2048 tail pad

// output offsets (floats)
constexpr size_t O1 = 2101244;   // oq
constexpr size_t O2 = 2109436;   // v_gain
constexpr size_t O3 = 2117628;   // u_gain
constexpr size_t O4 = 2125820;   // ff
constexpr size_t O5 = 2158588;   // fb

// workspace offsets (bytes)
constexpr size_t OFF_X      = 0;                 // 8192*512*4 ; af16 reuses this (dead after gemm)
constexpr size_t OFF_GI     = 16777216;          // 8192*1536*4
constexpr size_t OFF_OQ     = 83886080;
constexpr size_t OFF_VG     = 83918848;
constexpr size_t OFF_UG     = 83951616;
constexpr size_t OFF_FFW    = 83984384;
constexpr size_t OFF_FBW    = 84115456;
constexpr size_t OFF_START  = 84246528;
constexpr size_t OFF_F0M    = 84279296;
constexpr size_t OFF_HBUF   = 84283392;          // own 16KB now (gru writes ffw/fbw live — old overlay invalid)
constexpr size_t OFF_WTAP   = 50331648;          // Toeplitz IR MFMA fragments (770048B) — gi dead-zone
constexpr size_t OFF_AUDIO  = 92684800;          // 4*549376*4
constexpr size_t OFF_AF16   = OFF_X;             // packed f16 audio, 4*551424*2 = 4.41MB

__device__ __forceinline__ float softplusf(float x) {
  return x > 20.0f ? x : log1pf(expf(x));
}
__device__ __forceinline__ float sigmoidf_(float x) {
  return 1.0f / (1.0f + expf(-x));
}
__device__ __forceinline__ float fastrcp(float x) {
#if __has_builtin(__builtin_amdgcn_rcpf)
  return __builtin_amdgcn_rcpf(x);
#else
  return 1.0f / x;
#endif
}
__device__ __forceinline__ float fastsoftplus(float x) {
  return x > 20.0f ? x : __logf(1.0f + __expf(x));
}

typedef _Float16 half2v __attribute__((ext_vector_type(2)));
typedef _Float16 f16x8 __attribute__((ext_vector_type(8)));
typedef float f32x4 __attribute__((ext_vector_type(4)));

__device__ __forceinline__ float dot2f(unsigned wa, unsigned hb, float acc) {
#if __has_builtin(__builtin_amdgcn_fdot2)
  union { unsigned u; half2v h; } A, B;
  A.u = wa; B.u = hb;
  return __builtin_amdgcn_fdot2(A.h, B.h, acc, false);
#else
  union { unsigned u; _Float16 h[2]; } A, B;
  A.u = wa; B.u = hb;
  return fmaf((float)A.h[0], (float)B.h[0], fmaf((float)A.h[1], (float)B.h[1], acc));
#endif
}

// ---------------- f0 mean per batch ----------------
__global__ __launch_bounds__(256) void k_f0mean(const float* __restrict__ f0, float* __restrict__ f0m) {
  int b = blockIdx.x, tid = threadIdx.x;
  float s = 0.f;
  for (int t = tid; t < FF_; t += 256) s += f0[b*FF_ + t];
  #pragma unroll
  for (int m = 1; m < 64; m <<= 1) s += __shfl_xor(s, m);
  __shared__ float ws4[4];
  if ((tid & 63) == 0) ws4[tid >> 6] = s;
  __syncthreads();
  if (tid == 0) f0m[b] = (ws4[0] + ws4[1] + ws4[2] + ws4[3]) * (1.0f / 2048.0f);
}

// ---------------- input projection: x = relu(concat @ W_in^T + b_in) ----------------
__global__ __launch_bounds__(256) void k_inproj(
    const float* __restrict__ f0, const float* __restrict__ loud,
    const float* __restrict__ gender, const float* __restrict__ age,
    const float* __restrict__ z, const float* __restrict__ f0m,
    const float* __restrict__ Win, const float* __restrict__ bin,
    float* __restrict__ x)
{
  __shared__ float inp[16 * 28];
  int r0 = blockIdx.x * 16;   // bf base
  int tid = threadIdx.x;
  for (int i = tid; i < 16 * 28; i += 256) {
    int r = i / 28, c = i % 28;
    int bf = r0 + r, b = bf >> 11;
    float v;
    if (c == 0)       v = f0[bf] - f0m[b];
    else if (c == 1)  v = loud[bf];
    else if (c < 4)   v = gender[(size_t)bf*2 + (c - 2)];
    else if (c < 12)  v = age[(size_t)bf*8 + (c - 4)];
    else              v = z[(size_t)bf*16 + (c - 12)];
    inp[i] = v;
  }
  __syncthreads();
  for (int o = tid; o < 16 * 512; o += 256) {
    int r = o >> 9, j = o & 511;
    const float* w = Win + j * 28;
    const float* ip = inp + r * 28;
    float a = bin[j];
    #pragma unroll
    for (int c2 = 0; c2 < 28; ++c2) a = fmaf(w[c2], ip[c2], a);
    x[(size_t)(r0 + r) * 512 + j] = fmaxf(a, 0.0f);
  }
}

// ---------------- GEMM v2 (MFMA f16): gi = x @ W_ih^T + b_ih ----------------
__global__ __launch_bounds__(256) void k_gemm_gi(
    const float* __restrict__ A, const float* __restrict__ Bw,
    const float* __restrict__ bias, float* __restrict__ C)
{
  __shared__ unsigned As[64 * 20];  // f16-pair dwords, row stride 20
  __shared__ unsigned Bs[64 * 20];
  int tid = threadIdx.x;
  int n0 = blockIdx.x * 64, m0 = blockIdx.y * 64;
  const int w = tid >> 6;           // wave 0..3
  const int lane = tid & 63;
  const int mrow0 = (w >> 1) * 32;
  const int ncol0 = (w & 1) * 32;
  const int lm = lane & 15;
  const int quad = lane >> 4;

  f32x4 acc00 = {0.f,0.f,0.f,0.f}, acc01 = {0.f,0.f,0.f,0.f};
  f32x4 acc10 = {0.f,0.f,0.f,0.f}, acc11 = {0.f,0.f,0.f,0.f};

  for (int k0 = 0; k0 < 512; k0 += 32) {
    __syncthreads();
    for (int i = tid; i < 1024; i += 256) {
      int r = i >> 4, d = i & 15;
      float2 av = *(const float2*)(A + (size_t)(m0 + r) * 512 + k0 + 2 * d);
      float2 bv = *(const float2*)(Bw + (size_t)(n0 + r) * 512 + k0 + 2 * d);
      union { unsigned u32; _Float16 h[2]; } pa, pb;
      pa.h[0] = (_Float16)av.x; pa.h[1] = (_Float16)av.y;
      pb.h[0] = (_Float16)bv.x; pb.h[1] = (_Float16)bv.y;
      As[r * 20 + d] = pa.u32;
      Bs[r * 20 + d] = pb.u32;
    }
    __syncthreads();
    union { uint4 u; f16x8 h; } a0, a1, b0, b1;
    a0.u = *(const uint4*)&As[(mrow0 + lm) * 20 + quad * 4];
    a1.u = *(const uint4*)&As[(mrow0 + 16 + lm) * 20 + quad * 4];
    b0.u = *(const uint4*)&Bs[(ncol0 + lm) * 20 + quad * 4];
    b1.u = *(const uint4*)&Bs[(ncol0 + 16 + lm) * 20 + quad * 4];
    acc00 = __builtin_amdgcn_mfma_f32_16x16x32_f16(a0.h, b0.h, acc00, 0, 0, 0);
    acc01 = __builtin_amdgcn_mfma_f32_16x16x32_f16(a0.h, b1.h, acc01, 0, 0, 0);
    acc10 = __builtin_amdgcn_mfma_f32_16x16x32_f16(a1.h, b0.h, acc10, 0, 0, 0);
    acc11 = __builtin_amdgcn_mfma_f32_16x16x32_f16(a1.h, b1.h, acc11, 0, 0, 0);
  }
  #pragma unroll
  for (int sm = 0; sm < 2; ++sm) {
    #pragma unroll
    for (int sn = 0; sn < 2; ++sn) {
      const f32x4& ac = sm ? (sn ? acc11 : acc10) : (sn ? acc01 : acc00);
      int col = n0 + ncol0 + sn * 16 + lm;
      float bb = bias[col];
      #pragma unroll
      for (int rg = 0; rg < 4; ++rg) {
        int row = m0 + mrow0 + sm * 16 + quad * 4 + rg;
        C[(size_t)row * 1536 + col] = ac[rg] + bb;
      }
    }
  }
}

// ---------------- persistent GRU v13: v11 revert (2650us) + heads fused on wave 3 ----------------
// v11 geometry restored exactly: 64 WGs, b=(bid&7)>>1 XCD-pair map, 32 units/WG,
// single-load spin, 2 barriers, fast tail, hbuf-store-first. (R6's single-XCD map: −5%, reverted.)
// NEW: k_heads fused. Every WG sees the full 512-dim h in hs2 (the broadcast). Wave 3
// (tid 192..255, previously idle between barriers) computes the 11 head dots for frames
// f ≡ wgi (mod 16): at step t, hs2[t&1] = h_{t-1} -> WG with (t-1)&15==wgi handles frame t-1.
// Lane j=tid-192 <44: (head j>>2, 128-dim piece j&3), weights in w0r[64] (zeroed in v11).
// Quad shfl_xor reduce, 11 shfl gather, lane 192 does activations + out/work-array stores.
// hs array is DEAD (k_heads was its only consumer) -> tail's hs store removed too.
// Extra iteration t=2048 handles frame 2047 (tag 2048 exists; gru work guarded off).
__global__ __launch_bounds__(256, 1) void k_gru(
    const float* __restrict__ Whh, const float* __restrict__ bhh,
    const float* __restrict__ gi, unsigned long long* hbuf,
    const float* __restrict__ Woq, const float* __restrict__ boq,
    const float* __restrict__ Wvg, const float* __restrict__ bvg,
    const float* __restrict__ Wug, const float* __restrict__ bug,
    const float* __restrict__ Wff, const float* __restrict__ bff,
    const float* __restrict__ Wfb, const float* __restrict__ bfb,
    float* __restrict__ out,
    float* __restrict__ oqw, float* __restrict__ vgw, float* __restrict__ ugw,
    float* __restrict__ ffw, float* __restrict__ fbw)
{
  __shared__ unsigned hs2[2][292];   // 8 chunks x 36-dword stride per parity
  __shared__ float red[2][384];      // [row*4 + piece], 96 rows
  __shared__ float bhh_s[96];

  const int tid = threadIdx.x;
  const int bid = blockIdx.x;                        // 0..63
  const int b   = (bid & 7) >> 1;                    // batch -> XCD pair {2b,2b+1}
  const int wgi = ((bid >> 3) << 1) | (bid & 1);     // 0..15
  const int u0  = wgi * 32;
  const int piece = tid & 3;         // 128-dim piece (dot threads tid<192)
  const int rp    = tid >> 2;        // row pair 0..47

  unsigned w0r[64], w1r[64];
  float hb0 = 0.f, hb1 = 0.f, hb2 = 0.f;
  float hbf0 = 0.f, hbf1 = 0.f, hbf2 = 0.f, hbf3 = 0.f;
  float hbb0 = 0.f, hbb1 = 0.f, hbb2 = 0.f, hbb3 = 0.f;
  if (tid < 192) {
    int r0 = 2 * rp, r1 = 2 * rp + 1;                // rows 0..95 = gate*32 + unit
    const float* s0 = Whh + (size_t)((r0 >> 5) * 512 + u0 + (r0 & 31)) * 512 + piece * 128;
    const float* s1 = Whh + (size_t)((r1 >> 5) * 512 + u0 + (r1 & 31)) * 512 + piece * 128;
    #pragma unroll
    for (int j = 0; j < 64; ++j) {
      float2 a = *(const float2*)(s0 + 2 * j);
      float2 c = *(const float2*)(s1 + 2 * j);
      union { unsigned u32; _Float16 hh[2]; } ca, cb;
      ca.hh[0] = (_Float16)a.x; ca.hh[1] = (_Float16)a.y;
      cb.hh[0] = (_Float16)c.x; cb.hh[1] = (_Float16)c.y;
      w0r[j] = ca.u32; w1r[j] = cb.u32;
    }
  } else {
    int j = tid - 192;
    #pragma unroll
    for (int q = 0; q < 64; ++q) { w0r[q] = 0u; w1r[q] = 0u; }
    if (j < 44) {
      int hd = j >> 2, pc = j & 3;
      const float* rowp = (hd == 0) ? Woq : (hd == 1) ? Wvg : (hd == 2) ? Wug :
                          (hd < 7) ? (Wff + (size_t)(hd - 3) * 512)
                                   : (Wfb + (size_t)(hd - 7) * 512);
      const float* srcw = rowp + pc * 128;
      #pragma unroll
      for (int q = 0; q < 64; ++q) {
        float2 a = *(const float2*)(srcw + 2 * q);
        union { unsigned u32; _Float16 hh[2]; } ca;
        ca.hh[0] = (_Float16)a.x; ca.hh[1] = (_Float16)a.y;
        w0r[q] = ca.u32;
      }
    }
    if (j == 0) {
      hb0 = boq[0]; hb1 = bvg[0]; hb2 = bug[0];
      hbf0 = bff[0]; hbf1 = bff[1]; hbf2 = bff[2]; hbf3 = bff[3];
      hbb0 = bfb[0]; hbb1 = bfb[1]; hbb2 = bfb[2]; hbb3 = bfb[3];
    }
  }
  if (tid < 96) bhh_s[tid] = bhh[(tid >> 5) * 512 + u0 + (tid & 31)];
  __syncthreads();

  float hprev = 0.0f;

  #pragma unroll 1
  for (unsigned t = 0; t <= 2048; ++t) {
    const int p = (int)(t & 1u);
    float gir = 0.f, giz = 0.f, gin = 0.f;
    if (tid < 32 && t < 2048u) {
      const float* gp = gi + (size_t)(b * 2048 + (int)t) * 1536 + u0 + tid;
      gir = gp[0]; giz = gp[512]; gin = gp[1024];
    }
    {
      const unsigned long long* pp = hbuf + ((size_t)p * 4 + b) * 256 + tid;
      unsigned long long w = __hip_atomic_load(pp, __ATOMIC_RELAXED, __HIP_MEMORY_SCOPE_AGENT);
      while ((unsigned)(w >> 32) != t)
        w = __hip_atomic_load(pp, __ATOMIC_RELAXED, __HIP_MEMORY_SCOPE_AGENT);
      hs2[p][(tid >> 5) * 36 + (tid & 31)] = (unsigned)w;
    }
    __syncthreads();
    if (tid < 192 && t < 2048u) {
      const unsigned* hp0 = &hs2[p][(2 * piece) * 36];
      const unsigned* hp1 = &hs2[p][(2 * piece + 1) * 36];
      float a00 = 0.f, a01 = 0.f, a10 = 0.f, a11 = 0.f;
      #pragma unroll
      for (int i = 0; i < 8; ++i) {
        uint4 h4 = *(const uint4*)(hp0 + 4 * i);
        a00 = dot2f(w0r[4 * i + 0], h4.x, a00);
        a01 = dot2f(w0r[4 * i + 1], h4.y, a01);
        a00 = dot2f(w0r[4 * i + 2], h4.z, a00);
        a01 = dot2f(w0r[4 * i + 3], h4.w, a01);
        a10 = dot2f(w1r[4 * i + 0], h4.x, a10);
        a11 = dot2f(w1r[4 * i + 1], h4.y, a11);
        a10 = dot2f(w1r[4 * i + 2], h4.z, a10);
        a11 = dot2f(w1r[4 * i + 3], h4.w, a11);
      }
      #pragma unroll
      for (int i = 0; i < 8; ++i) {
        uint4 h4 = *(const uint4*)(hp1 + 4 * i);
        a00 = dot2f(w0r[32 + 4 * i + 0], h4.x, a00);
        a01 = dot2f(w0r[32 + 4 * i + 1], h4.y, a01);
        a00 = dot2f(w0r[32 + 4 * i + 2], h4.z, a00);
        a01 = dot2f(w0r[32 + 4 * i + 3], h4.w, a01);
        a10 = dot2f(w1r[32 + 4 * i + 0], h4.x, a10);
        a11 = dot2f(w1r[32 + 4 * i + 1], h4.y, a11);
        a10 = dot2f(w1r[32 + 4 * i + 2], h4.z, a10);
        a11 = dot2f(w1r[32 + 4 * i + 3], h4.w, a11);
      }
      red[p][(2 * rp) * 4 + piece]     = a00 + a01;
      red[p][(2 * rp + 1) * 4 + piece] = a10 + a11;
    }
    // ---- fused heads on wave 3 (tid 192..255): frame fr = t-1 when fr%16 == wgi ----
    if (tid >= 192 && t >= 1u && (int)((t - 1u) & 15u) == wgi) {
      unsigned fr = t - 1u;
      int j = tid - 192;
      int pc = j & 3;
      const unsigned* hh0 = &hs2[p][(2 * pc) * 36];
      const unsigned* hh1 = &hs2[p][(2 * pc + 1) * 36];
      float a0 = 0.f, a1 = 0.f;
      #pragma unroll
      for (int i = 0; i < 8; ++i) {
        uint4 h4 = *(const uint4*)(hh0 + 4 * i);
        a0 = dot2f(w0r[4 * i + 0], h4.x, a0);
        a1 = dot2f(w0r[4 * i + 1], h4.y, a1);
        a0 = dot2f(w0r[4 * i + 2], h4.z, a0);
        a1 = dot2f(w0r[4 * i + 3], h4.w, a1);
      }
      #pragma unroll
      for (int i = 0; i < 8; ++i) {
        uint4 h4 = *(const uint4*)(hh1 + 4 * i);
        a0 = dot2f(w0r[32 + 4 * i + 0], h4.x, a0);
        a1 = dot2f(w0r[32 + 4 * i + 1], h4.y, a1);
        a0 = dot2f(w0r[32 + 4 * i + 2], h4.z, a0);
        a1 = dot2f(w0r[32 + 4 * i + 3], h4.w, a1);
      }
      float vs = a0 + a1;
      vs += __shfl_xor(vs, 1);
      vs += __shfl_xor(vs, 2);     // all 4 lanes of a quad hold the head sum
      float s0 = __shfl(vs, 0),  s1 = __shfl(vs, 4),  s2 = __shfl(vs, 8);
      float s3 = __shfl(vs, 12), s4 = __shfl(vs, 16), s5 = __shfl(vs, 20);
      float s6 = __shfl(vs, 24), s7 = __shfl(vs, 28), s8 = __shfl(vs, 32);
      float s9 = __shfl(vs, 36), s10 = __shfl(vs, 40);
      if (j == 0) {
        size_t bf = (size_t)b * 2048 + fr;
        float oqv = fastrcp(1.0f + __expf(-(s0 + hb0)));
        float vg = fastsoftplus(s1 + hb1);
        float ug = fastsoftplus(s2 + hb2);
        out[O1 + bf] = oqv; oqw[bf] = oqv;
        out[O2 + bf] = vg;  vgw[bf] = vg;
        out[O3 + bf] = ug;  ugw[bf] = ug;
        float run = 200.0f;
        run += fastsoftplus(s3 + hbf0); out[O4 + bf * 4 + 0] = run; ffw[bf * 4 + 0] = run;
        run += fastsoftplus(s4 + hbf1); out[O4 + bf * 4 + 1] = run; ffw[bf * 4 + 1] = run;
        run += fastsoftplus(s5 + hbf2); out[O4 + bf * 4 + 2] = run; ffw[bf * 4 + 2] = run;
        run += fastsoftplus(s6 + hbf3); out[O4 + bf * 4 + 3] = run; ffw[bf * 4 + 3] = run;
        float g0 = fastsoftplus(s7 + hbb0) + 50.0f;  out[O5 + bf * 4 + 0] = g0; fbw[bf * 4 + 0] = g0;
        float g1 = fastsoftplus(s8 + hbb1) + 50.0f;  out[O5 + bf * 4 + 1] = g1; fbw[bf * 4 + 1] = g1;
        float g2 = fastsoftplus(s9 + hbb2) + 50.0f;  out[O5 + bf * 4 + 2] = g2; fbw[bf * 4 + 2] = g2;
        float g3 = fastsoftplus(s10 + hbb3) + 50.0f; out[O5 + bf * 4 + 3] = g3; fbw[bf * 4 + 3] = g3;
      }
    }
    __syncthreads();
    if (tid < 32 && t < 2048u) {
      float4 q0 = *(const float4*)&red[p][tid * 4];
      float4 z0 = *(const float4*)&red[p][(32 + tid) * 4];
      float4 n0 = *(const float4*)&red[p][(64 + tid) * 4];
      float ghr = ((q0.x + q0.y) + (q0.z + q0.w)) + bhh_s[tid];
      float ghz = ((z0.x + z0.y) + (z0.z + z0.w)) + bhh_s[32 + tid];
      float ghn = ((n0.x + n0.y) + (n0.z + n0.w)) + bhh_s[64 + tid];
      float r  = fastrcp(1.0f + __expf(-(gir + ghr)));
      float zg = fastrcp(1.0f + __expf(-(giz + ghz)));
      float e2 = __expf(2.0f * (gin + r * ghn));
      float n  = 1.0f - 2.0f * fastrcp(e2 + 1.0f);
      float hnew = (1.0f - zg) * n + zg * hprev;
      hprev = hnew;
      float hpart = __shfl_xor(hnew, 1);
      if ((tid & 1) == 0) {
        union { unsigned u32; _Float16 hh[2]; } pk;
        pk.hh[0] = (_Float16)hnew;
        pk.hh[1] = (_Float16)hpart;
        unsigned long long wq = ((unsigned long long)(t + 1u) << 32) | (unsigned long long)pk.u32;
        __hip_atomic_store(hbuf + ((size_t)((t + 1u) & 1u) * 4 + b) * 256 + (u0 >> 1) + (tid >> 1),
                           wq, __ATOMIC_RELAXED, __HIP_MEMORY_SCOPE_AGENT);
      }
    }
  }
}

// ---------------- per-batch prefix scan of cycles -> start phase ----------------
__global__ __launch_bounds__(256) void k_scan(const float* __restrict__ f0, float* __restrict__ startw) {
  __shared__ float ts[256];
  int b = blockIdx.x, tid = threadIdx.x;
  const float CY = 256.0f / 24000.0f;
  float c[8], run = 0.f;
  int base = b * 2048 + tid * 8;
  #pragma unroll
  for (int j = 0; j < 8; ++j) { c[j] = run; run += f0[base + j] * CY; }
  ts[tid] = run;
  __syncthreads();
  for (int off = 1; off < 256; off <<= 1) {
    float v = (tid >= off) ? ts[tid - off] : 0.0f;
    __syncthreads();
    ts[tid] += v;
    __syncthreads();
  }
  float excl = (tid == 0) ? 0.0f : ts[tid - 1];
  #pragma unroll
  for (int j = 0; j < 8; ++j) {
    float st = excl + c[j];
    startw[base + j] = st - floorf(st);
  }
}

// ---------------- fused synth: excitation + formant IR + conv/OLA ----------------
// fast-math trig: __sinf/__cosf/__expf (args <= ~64 revolutions, err ~1e-4 << f16 path)
__global__ __launch_bounds__(256) void k_synth(
    const float* __restrict__ f0, const float* __restrict__ noise,
    const float* __restrict__ startw, const float* __restrict__ oqw,
    const float* __restrict__ vgw, const float* __restrict__ ugw,
    const float* __restrict__ ffw, const float* __restrict__ fbw,
    float* __restrict__ audio)
{
  __shared__ float es[256];
  __shared__ float fp[1536];
  __shared__ float ffs[4], fbs[4], ssc[1], wmax[4];
  int bf = blockIdx.x, tid = threadIdx.x;
  int b = bf >> 11, f = bf & 2047;

  // excitation -> es
  {
    float st = startw[bf], f0v = f0[bf], oqv = oqw[bf], vg = vgw[bf], ug = ugw[bf];
    float total = st + f0v * ((float)tid * (1.0f / 24000.0f));
    float phi = total - floorf(total);
    float peak = oqv * 0.66f;
    float rise = 0.5f * (1.0f - __cosf(PI_F * phi / (peak + 1e-6f)));
    float fall = __cosf(PI_F * (phi - peak) / (2.0f * (oqv - peak) + 1e-6f));
    float v = (phi < peak) ? rise : ((phi < oqv) ? fall : 0.0f);
    es[tid] = v * vg + noise[(size_t)bf * 256 + tid] * ug;
  }
  if (tid < 4) { ffs[tid] = ffw[(size_t)bf * 4 + tid]; fbs[tid] = fbw[(size_t)bf * 4 + tid]; }
  fp[tid] = 0.0f;          // fp[0..255]
  fp[1280 + tid] = 0.0f;   // fp[1280..1535]
  __syncthreads();

  // formant IR + normalization -> fp[256..1279] reversed
  float vals[4];
  float am = 0.f;
  #pragma unroll
  for (int it = 0; it < 4; ++it) {
    int k = it * 256 + tid;
    float t = (float)k * (1.0f / 24000.0f);
    float s = 0.f;
    #pragma unroll
    for (int j = 0; j < 4; ++j)
      s += __expf(-PI_F * fbs[j] * t) * __sinf(TWO_PI_F * ffs[j] * t);
    vals[it] = s;
    am = fmaxf(am, fabsf(s));
  }
  #pragma unroll
  for (int m = 1; m < 64; m <<= 1) am = fmaxf(am, __shfl_xor(am, m));
  if ((tid & 63) == 0) wmax[tid >> 6] = am;
  __syncthreads();
  if (tid == 0) ssc[0] = fmaxf(fmaxf(wmax[0], wmax[1]), fmaxf(wmax[2], wmax[3])) + 1e-8f;
  __syncthreads();
  float inv = 1.0f / ssc[0];
  #pragma unroll
  for (int it = 0; it < 4; ++it) {
    int k = it * 256 + tid;
    fp[256 + (1023 - k)] = vals[it] * inv;
  }
  __syncthreads();

  // conv (full) + overlap-add
  int n0 = tid * 5;
  float V0 = fp[n0 + 256], V1 = fp[n0 + 257], V2 = fp[n0 + 258], V3 = fp[n0 + 259], V4 = fp[n0 + 260];
  float a0 = 0.f, a1 = 0.f, a2 = 0.f, a3 = 0.f, a4 = 0.f;
  #pragma unroll 4
  for (int m = 0; m < 256; ++m) {
    float e = es[m];
    a0 = fmaf(e, V0, a0); a1 = fmaf(e, V1, a1); a2 = fmaf(e, V2, a2);
    a3 = fmaf(e, V3, a3); a4 = fmaf(e, V4, a4);
    V4 = V3; V3 = V2; V2 = V1; V1 = V0;
    V0 = fp[n0 + 255 - m];
  }
  float* arow = audio + (size_t)b * AROW + APAD + (size_t)f * 256;
  if (n0 + 0 < LL) atomicAdd(&arow[n0 + 0], a0);
  if (n0 + 1 < LL) atomicAdd(&arow[n0 + 1], a1);
  if (n0 + 2 < LL) atomicAdd(&arow[n0 + 2], a2);
  if (n0 + 3 < LL) atomicAdd(&arow[n0 + 3], a3);
  if (n0 + 4 < LL) atomicAdd(&arow[n0 + 4], a4);
}

// ---------------- pack audio fp32 -> f16 halves (row stride AROW2, zero tail pad) ----------------
__global__ __launch_bounds__(256) void k_packaudio(const float* __restrict__ audio,
                                                   unsigned* __restrict__ af) {
  int idx = blockIdx.x * 256 + threadIdx.x;   // dword index (2 halves)
  int b = blockIdx.y;
  size_t i0 = (size_t)idx * 2;
  if (i0 < AROW2) {
    float a = (i0 < AROW)     ? audio[(size_t)b * AROW + i0]     : 0.0f;
    float c = (i0 + 1 < AROW) ? audio[(size_t)b * AROW + i0 + 1] : 0.0f;
    union { unsigned u32; _Float16 h[2]; } pk;
    pk.h[0] = (_Float16)a; pk.h[1] = (_Float16)c;
    af[(size_t)b * (AROW2 / 2) + idx] = pk.u32;
  }
}

// ---------------- Toeplitz IR fragments for MFMA reverb ----------------
// W_p[r][k] = ir[32p + 16 + r - k], r in [0,16), k in [0,32), zero outside [0,REV).
// Fragment layout (= working k_gemm_gi A-operand): lane l holds r = l&15,
// k = (l>>4)*8 + i for i in 0..7, packed as 4 dwords (h[2j] = low half of dword j).
__global__ __launch_bounds__(256) void k_wtaps(const float* __restrict__ ir, uint4* __restrict__ wtap) {
  int g = blockIdx.x * 256 + threadIdx.x;
  int p = g >> 6, l = g & 63;
  if (p < 752) {
    int base = 32 * p + 16 + (l & 15) - ((l >> 4) << 3);
    unsigned dw[4];
    #pragma unroll
    for (int j = 0; j < 4; ++j) {
      int i0 = base - 2 * j, i1 = base - 2 * j - 1;
      float v0 = (i0 >= 0 && i0 < REV) ? ir[i0] : 0.0f;
      float v1 = (i1 >= 0 && i1 < REV) ? ir[i1] : 0.0f;
      union { unsigned u32; _Float16 h[2]; } pk;
      pk.h[0] = (_Float16)v0; pk.h[1] = (_Float16)v1;
      dw[j] = pk.u32;
    }
    uint4 o; o.x = dw[0]; o.y = dw[1]; o.z = dw[2]; o.w = dw[3];
    wtap[(size_t)(p << 6) + l] = o;
  }
}

// ---------------- reverb v6: block-Toeplitz MFMA conv ----------------
constexpr int PC = 16;       // tap-pairs per chunk
constexpr int NCHUNK = 47;   // covers p 0..751 (752 padded with zeros)
constexpr int WINH = 2544;   // window halves: 32*(PC-1) + 2064

__global__ __launch_bounds__(256) void k_reverb(
    const float* __restrict__ audio, const unsigned short* __restrict__ af,
    const uint4* __restrict__ wtap, const float* __restrict__ wetl,
    float* __restrict__ out)
{
  __shared__ __align__(16) unsigned short win[WINH];
  __shared__ uint4 wlds[PC * 64];
  int tb = blockIdx.x, b = blockIdx.y, tid = threadIdx.x;
  const int wv = tid >> 6, lane = tid & 63;
  const int lm = lane & 15, quad = lane >> 4;
  int q0 = tb * 128;
  const unsigned short* afrow = af + (size_t)b * AROW2;
  f32x4 acc0 = {0.f,0.f,0.f,0.f}, acc1 = {0.f,0.f,0.f,0.f};

  for (int c = 0; c < NCHUNK; ++c) {
    int p0 = c * PC;
    int b_lo = 16 * q0 - 32 * (p0 + PC - 1) - 16;        // >= -24048; APAD covers it
    const uint4* src = (const uint4*)(afrow + (APAD + b_lo));
    __syncthreads();
    for (int u = tid; u < 318 + PC * 64; u += 256) {
      if (u < 318) ((uint4*)win)[u] = src[u];
      else         wlds[u - 318] = wtap[(size_t)p0 * 64 + (u - 318)];
    }
    __syncthreads();
    int offb = 16 * lm + 8 * quad;
    int tA = (2 * wv) * 256 + offb, tB = (2 * wv + 1) * 256 + offb;
    #pragma unroll 4
    for (int pl = 0; pl < PC; ++pl) {
      union { uint4 u; f16x8 h; } wf, b0, b1;
      wf.u = wlds[pl * 64 + lane];
      int offp = 32 * (PC - 1 - pl);
      b0.u = *(const uint4*)&win[offp + tA];
      b1.u = *(const uint4*)&win[offp + tB];
      acc0 = __builtin_amdgcn_mfma_f32_16x16x32_f16(wf.h, b0.h, acc0, 0, 0, 0);
      acc1 = __builtin_amdgcn_mfma_f32_16x16x32_f16(wf.h, b1.h, acc1, 0, 0, 0);
    }
  }
  float wet = sigmoidf_(wetl[0]);
  const float* arow = audio + (size_t)b * AROW;
  #pragma unroll
  for (int tile = 0; tile < 2; ++tile) {
    const f32x4& ac = tile ? acc1 : acc0;
    int qt = q0 + (2 * wv + tile) * 16 + lm;
    #pragma unroll
    for (int rg = 0; rg < 4; ++rg) {
      long t = (long)16 * qt + quad * 4 + rg;
      if (t < (long)TOT) {
        float av = arow[APAD + t];
        out[(size_t)b * TOT + t] = (1.0f - wet) * av + wet * ac[rg];
      }
    }
  }
}

// ---------------- launch ----------------
extern "C" void kernel_launch(void* const* d_in, const int* in_sizes, int n_in,
                              void* d_out, int out_size, void* d_ws, size_t ws_size,
                              hipStream_t stream) {
  const float* f0       = (const float*)d_in[0];
  const float* loud     = (const float*)d_in[1];
  const float* gender   = (const float*)d_in[2];
  const float* age      = (const float*)d_in[3];
  const float* z        = (const float*)d_in[4];
  const float* noise    = (const float*)d_in[5];
  const float* W_in     = (const float*)d_in[6];
  const float* b_in     = (const float*)d_in[7];
  const float* W_ih     = (const float*)d_in[8];
  const float* W_hh     = (const float*)d_in[9];
  const float* b_ih     = (const float*)d_in[10];
  const float* b_hh     = (const float*)d_in[11];
  const float* W_oq     = (const float*)d_in[12];
  const float* b_oq     = (const float*)d_in[13];
  const float* W_vg     = (const float*)d_in[14];
  const float* b_vg     = (const float*)d_in[15];
  const float* W_ug     = (const float*)d_in[16];
  const float* b_ug     = (const float*)d_in[17];
  const float* W_ff     = (const float*)d_in[18];
  const float* b_ff     = (const float*)d_in[19];
  const float* W_fb     = (const float*)d_in[20];
  const float* b_fb     = (const float*)d_in[21];
  const float* rev_ir   = (const float*)d_in[22];
  const float* wet_l    = (const float*)d_in[23];

  float* out = (float*)d_out;
  char* ws = (char*)d_ws;
  float* x      = (float*)(ws + OFF_X);
  float* gi     = (float*)(ws + OFF_GI);
  float* oqw    = (float*)(ws + OFF_OQ);
  float* vgw    = (float*)(ws + OFF_VG);
  float* ugw    = (float*)(ws + OFF_UG);
  float* ffw    = (float*)(ws + OFF_FFW);
  float* fbw    = (float*)(ws + OFF_FBW);
  float* startw = (float*)(ws + OFF_START);
  float* f0m    = (float*)(ws + OFF_F0M);
  unsigned long long* hbuf = (unsigned long long*)(ws + OFF_HBUF);
  uint4* wtap   = (uint4*)(ws + OFF_WTAP);
  unsigned* af  = (unsigned*)(ws + OFF_AF16);
  float* audio  = (float*)(ws + OFF_AUDIO);

  // zero tagged h double-buffer (16KB, own region now) + audio acc
  hipMemsetAsync(ws + OFF_HBUF, 0, 16384, stream);
  hipMemsetAsync(ws + OFF_AUDIO, 0, (size_t)4 * AROW * 4, stream);

  k_f0mean<<<4, 256, 0, stream>>>(f0, f0m);
  k_inproj<<<512, 256, 0, stream>>>(f0, loud, gender, age, z, f0m, W_in, b_in, x);
  k_gemm_gi<<<dim3(24, 128), 256, 0, stream>>>(x, W_ih, b_ih, gi);
  k_gru<<<64, 256, 0, stream>>>(W_hh, b_hh, gi, hbuf,
                                W_oq, b_oq, W_vg, b_vg, W_ug, b_ug,
                                W_ff, b_ff, W_fb, b_fb,
                                out, oqw, vgw, ugw, ffw, fbw);
  k_scan<<<4, 256, 0, stream>>>(f0, startw);
  k_wtaps<<<188, 256, 0, stream>>>(rev_ir, wtap);      // gi region dead after k_gru
  k_synth<<<8192, 256, 0, stream>>>(f0, noise, startw, oqw, vgw, ugw, ffw, fbw, audio);
  k_packaudio<<<dim3(1077, 4), 256, 0, stream>>>(audio, af);  // x region dead after gemm
  k_reverb<<<dim3(257, 4), 256, 0, stream>>>(audio, (const unsigned short*)af, wtap, wet_l, out);
}

// Round 9
// 3355.315 us; speedup vs baseline: 1.1614x; 1.1614x over previous
//
#include <hip/hip_runtime.h>
#include <hip/hip_bf16.h>
#include <math.h>

// ---------------- constants ----------------
#define PI_F 3.14159265358979323846f
#define TWO_PI_F 6.283185307179586f

constexpr int BB = 4;            // batch
constexpr int FF_ = 2048;        // frames
constexpr int RC = 512;          // rnn channels
constexpr int HOP = 256;
constexpr int KK = 1024;         // FIR len
constexpr int LL = HOP + KK - 1; // 1279
constexpr size_t TOT = 525311;   // (F-1)*HOP + L
constexpr int APAD = 24064;      // zero pad in front of audio rows (>= REV-1, mult of 64)
constexpr size_t AROW = 549376;  // APAD + 525312
constexpr int REV = 24000;
constexpr size_t AROW2 = 551424; // af16 row halves: AROW + 2048 tail pad

// output offsets (floats)
constexpr size_t O1 = 2101244;   // oq
constexpr size_t O2 = 2109436;   // v_gain
constexpr size_t O3 = 2117628;   // u_gain
constexpr size_t O4 = 2125820;   // ff
constexpr size_t O5 = 2158588;   // fb

// workspace offsets (bytes)
constexpr size_t OFF_X      = 0;                 // 8192*512*4 ; af16 reuses this (dead after gemm)
constexpr size_t OFF_GI     = 16777216;          // 8192*1536*4
constexpr size_t OFF_OQ     = 83886080;
constexpr size_t OFF_VG     = 83918848;
constexpr size_t OFF_UG     = 83951616;
constexpr size_t OFF_FFW    = 83984384;
constexpr size_t OFF_FBW    = 84115456;
constexpr size_t OFF_START  = 84246528;
constexpr size_t OFF_F0M    = 84279296;
constexpr size_t OFF_HBUF   = 84283392;          // own 16KB (gru writes ffw/fbw live)
constexpr size_t OFF_WTAP   = 50331648;          // Toeplitz IR MFMA fragments (770048B) — gi dead-zone
constexpr size_t OFF_AUDIO  = 92684800;          // 4*549376*4
constexpr size_t OFF_AF16   = OFF_X;             // packed f16 audio, 4*551424*2 = 4.41MB

__device__ __forceinline__ float softplusf(float x) {
  return x > 20.0f ? x : log1pf(expf(x));
}
__device__ __forceinline__ float sigmoidf_(float x) {
  return 1.0f / (1.0f + expf(-x));
}
__device__ __forceinline__ float fastrcp(float x) {
#if __has_builtin(__builtin_amdgcn_rcpf)
  return __builtin_amdgcn_rcpf(x);
#else
  return 1.0f / x;
#endif
}
__device__ __forceinline__ float fastsoftplus(float x) {
  return x > 20.0f ? x : __logf(1.0f + __expf(x));
}

typedef _Float16 half2v __attribute__((ext_vector_type(2)));
typedef _Float16 f16x8 __attribute__((ext_vector_type(8)));
typedef float f32x4 __attribute__((ext_vector_type(4)));

__device__ __forceinline__ float dot2f(unsigned wa, unsigned hb, float acc) {
#if __has_builtin(__builtin_amdgcn_fdot2)
  union { unsigned u; half2v h; } A, B;
  A.u = wa; B.u = hb;
  return __builtin_amdgcn_fdot2(A.h, B.h, acc, false);
#else
  union { unsigned u; _Float16 h[2]; } A, B;
  A.u = wa; B.u = hb;
  return fmaf((float)A.h[0], (float)B.h[0], fmaf((float)A.h[1], (float)B.h[1], acc));
#endif
}

// ---------------- f0 mean per batch ----------------
__global__ __launch_bounds__(256) void k_f0mean(const float* __restrict__ f0, float* __restrict__ f0m) {
  int b = blockIdx.x, tid = threadIdx.x;
  float s = 0.f;
  for (int t = tid; t < FF_; t += 256) s += f0[b*FF_ + t];
  #pragma unroll
  for (int m = 1; m < 64; m <<= 1) s += __shfl_xor(s, m);
  __shared__ float ws4[4];
  if ((tid & 63) == 0) ws4[tid >> 6] = s;
  __syncthreads();
  if (tid == 0) f0m[b] = (ws4[0] + ws4[1] + ws4[2] + ws4[3]) * (1.0f / 2048.0f);
}

// ---------------- input projection: x = relu(concat @ W_in^T + b_in) ----------------
__global__ __launch_bounds__(256) void k_inproj(
    const float* __restrict__ f0, const float* __restrict__ loud,
    const float* __restrict__ gender, const float* __restrict__ age,
    const float* __restrict__ z, const float* __restrict__ f0m,
    const float* __restrict__ Win, const float* __restrict__ bin,
    float* __restrict__ x)
{
  __shared__ float inp[16 * 28];
  int r0 = blockIdx.x * 16;   // bf base
  int tid = threadIdx.x;
  for (int i = tid; i < 16 * 28; i += 256) {
    int r = i / 28, c = i % 28;
    int bf = r0 + r, b = bf >> 11;
    float v;
    if (c == 0)       v = f0[bf] - f0m[b];
    else if (c == 1)  v = loud[bf];
    else if (c < 4)   v = gender[(size_t)bf*2 + (c - 2)];
    else if (c < 12)  v = age[(size_t)bf*8 + (c - 4)];
    else              v = z[(size_t)bf*16 + (c - 12)];
    inp[i] = v;
  }
  __syncthreads();
  for (int o = tid; o < 16 * 512; o += 256) {
    int r = o >> 9, j = o & 511;
    const float* w = Win + j * 28;
    const float* ip = inp + r * 28;
    float a = bin[j];
    #pragma unroll
    for (int c2 = 0; c2 < 28; ++c2) a = fmaf(w[c2], ip[c2], a);
    x[(size_t)(r0 + r) * 512 + j] = fmaxf(a, 0.0f);
  }
}

// ---------------- GEMM v2 (MFMA f16): gi = x @ W_ih^T + b_ih ----------------
__global__ __launch_bounds__(256) void k_gemm_gi(
    const float* __restrict__ A, const float* __restrict__ Bw,
    const float* __restrict__ bias, float* __restrict__ C)
{
  __shared__ unsigned As[64 * 20];  // f16-pair dwords, row stride 20
  __shared__ unsigned Bs[64 * 20];
  int tid = threadIdx.x;
  int n0 = blockIdx.x * 64, m0 = blockIdx.y * 64;
  const int w = tid >> 6;           // wave 0..3
  const int lane = tid & 63;
  const int mrow0 = (w >> 1) * 32;
  const int ncol0 = (w & 1) * 32;
  const int lm = lane & 15;
  const int quad = lane >> 4;

  f32x4 acc00 = {0.f,0.f,0.f,0.f}, acc01 = {0.f,0.f,0.f,0.f};
  f32x4 acc10 = {0.f,0.f,0.f,0.f}, acc11 = {0.f,0.f,0.f,0.f};

  for (int k0 = 0; k0 < 512; k0 += 32) {
    __syncthreads();
    for (int i = tid; i < 1024; i += 256) {
      int r = i >> 4, d = i & 15;
      float2 av = *(const float2*)(A + (size_t)(m0 + r) * 512 + k0 + 2 * d);
      float2 bv = *(const float2*)(Bw + (size_t)(n0 + r) * 512 + k0 + 2 * d);
      union { unsigned u32; _Float16 h[2]; } pa, pb;
      pa.h[0] = (_Float16)av.x; pa.h[1] = (_Float16)av.y;
      pb.h[0] = (_Float16)bv.x; pb.h[1] = (_Float16)bv.y;
      As[r * 20 + d] = pa.u32;
      Bs[r * 20 + d] = pb.u32;
    }
    __syncthreads();
    union { uint4 u; f16x8 h; } a0, a1, b0, b1;
    a0.u = *(const uint4*)&As[(mrow0 + lm) * 20 + quad * 4];
    a1.u = *(const uint4*)&As[(mrow0 + 16 + lm) * 20 + quad * 4];
    b0.u = *(const uint4*)&Bs[(ncol0 + lm) * 20 + quad * 4];
    b1.u = *(const uint4*)&Bs[(ncol0 + 16 + lm) * 20 + quad * 4];
    acc00 = __builtin_amdgcn_mfma_f32_16x16x32_f16(a0.h, b0.h, acc00, 0, 0, 0);
    acc01 = __builtin_amdgcn_mfma_f32_16x16x32_f16(a0.h, b1.h, acc01, 0, 0, 0);
    acc10 = __builtin_amdgcn_mfma_f32_16x16x32_f16(a1.h, b0.h, acc10, 0, 0, 0);
    acc11 = __builtin_amdgcn_mfma_f32_16x16x32_f16(a1.h, b1.h, acc11, 0, 0, 0);
  }
  #pragma unroll
  for (int sm = 0; sm < 2; ++sm) {
    #pragma unroll
    for (int sn = 0; sn < 2; ++sn) {
      const f32x4& ac = sm ? (sn ? acc11 : acc10) : (sn ? acc01 : acc00);
      int col = n0 + ncol0 + sn * 16 + lm;
      float bb = bias[col];
      #pragma unroll
      for (int rg = 0; rg < 4; ++rg) {
        int row = m0 + mrow0 + sm * 16 + quad * 4 + rg;
        C[(size_t)row * 1536 + col] = ac[rg] + bb;
      }
    }
  }
}

// ---------------- persistent GRU v14: v13 with heads moved AFTER the store ----------------
// R7 lesson: head work between barrier1/barrier2 delayed the producing WG's hbuf store by
// ~500cy EVERY step (rotating wgi) -> +340cy/step on the global critical path. Fix: head
// block now runs at the END of the iteration, after barrier2 and the tail store. The store
// issues first; wave 3's head work for frame t-1 overlaps the next iteration's poll window
// (detect ~900cy > head work ~500cy, so it hides). hs2[p] stays valid until step t+2's poll,
// and wave 3 itself performs that write -> sequentially safe. Everything else = v11/v13.
__global__ __launch_bounds__(256, 1) void k_gru(
    const float* __restrict__ Whh, const float* __restrict__ bhh,
    const float* __restrict__ gi, unsigned long long* hbuf,
    const float* __restrict__ Woq, const float* __restrict__ boq,
    const float* __restrict__ Wvg, const float* __restrict__ bvg,
    const float* __restrict__ Wug, const float* __restrict__ bug,
    const float* __restrict__ Wff, const float* __restrict__ bff,
    const float* __restrict__ Wfb, const float* __restrict__ bfb,
    float* __restrict__ out,
    float* __restrict__ oqw, float* __restrict__ vgw, float* __restrict__ ugw,
    float* __restrict__ ffw, float* __restrict__ fbw)
{
  __shared__ unsigned hs2[2][292];   // 8 chunks x 36-dword stride per parity
  __shared__ float red[2][384];      // [row*4 + piece], 96 rows
  __shared__ float bhh_s[96];

  const int tid = threadIdx.x;
  const int bid = blockIdx.x;                        // 0..63
  const int b   = (bid & 7) >> 1;                    // batch -> XCD pair {2b,2b+1}
  const int wgi = ((bid >> 3) << 1) | (bid & 1);     // 0..15
  const int u0  = wgi * 32;
  const int piece = tid & 3;         // 128-dim piece (dot threads tid<192)
  const int rp    = tid >> 2;        // row pair 0..47

  unsigned w0r[64], w1r[64];
  float hb0 = 0.f, hb1 = 0.f, hb2 = 0.f;
  float hbf0 = 0.f, hbf1 = 0.f, hbf2 = 0.f, hbf3 = 0.f;
  float hbb0 = 0.f, hbb1 = 0.f, hbb2 = 0.f, hbb3 = 0.f;
  if (tid < 192) {
    int r0 = 2 * rp, r1 = 2 * rp + 1;                // rows 0..95 = gate*32 + unit
    const float* s0 = Whh + (size_t)((r0 >> 5) * 512 + u0 + (r0 & 31)) * 512 + piece * 128;
    const float* s1 = Whh + (size_t)((r1 >> 5) * 512 + u0 + (r1 & 31)) * 512 + piece * 128;
    #pragma unroll
    for (int j = 0; j < 64; ++j) {
      float2 a = *(const float2*)(s0 + 2 * j);
      float2 c = *(const float2*)(s1 + 2 * j);
      union { unsigned u32; _Float16 hh[2]; } ca, cb;
      ca.hh[0] = (_Float16)a.x; ca.hh[1] = (_Float16)a.y;
      cb.hh[0] = (_Float16)c.x; cb.hh[1] = (_Float16)c.y;
      w0r[j] = ca.u32; w1r[j] = cb.u32;
    }
  } else {
    int j = tid - 192;
    #pragma unroll
    for (int q = 0; q < 64; ++q) { w0r[q] = 0u; w1r[q] = 0u; }
    if (j < 44) {
      int hd = j >> 2, pc = j & 3;
      const float* rowp = (hd == 0) ? Woq : (hd == 1) ? Wvg : (hd == 2) ? Wug :
                          (hd < 7) ? (Wff + (size_t)(hd - 3) * 512)
                                   : (Wfb + (size_t)(hd - 7) * 512);
      const float* srcw = rowp + pc * 128;
      #pragma unroll
      for (int q = 0; q < 64; ++q) {
        float2 a = *(const float2*)(srcw + 2 * q);
        union { unsigned u32; _Float16 hh[2]; } ca;
        ca.hh[0] = (_Float16)a.x; ca.hh[1] = (_Float16)a.y;
        w0r[q] = ca.u32;
      }
    }
    if (j == 0) {
      hb0 = boq[0]; hb1 = bvg[0]; hb2 = bug[0];
      hbf0 = bff[0]; hbf1 = bff[1]; hbf2 = bff[2]; hbf3 = bff[3];
      hbb0 = bfb[0]; hbb1 = bfb[1]; hbb2 = bfb[2]; hbb3 = bfb[3];
    }
  }
  if (tid < 96) bhh_s[tid] = bhh[(tid >> 5) * 512 + u0 + (tid & 31)];
  __syncthreads();

  float hprev = 0.0f;

  #pragma unroll 1
  for (unsigned t = 0; t <= 2048; ++t) {
    const int p = (int)(t & 1u);
    float gir = 0.f, giz = 0.f, gin = 0.f;
    if (tid < 32 && t < 2048u) {
      const float* gp = gi + (size_t)(b * 2048 + (int)t) * 1536 + u0 + tid;
      gir = gp[0]; giz = gp[512]; gin = gp[1024];
    }
    {
      const unsigned long long* pp = hbuf + ((size_t)p * 4 + b) * 256 + tid;
      unsigned long long w = __hip_atomic_load(pp, __ATOMIC_RELAXED, __HIP_MEMORY_SCOPE_AGENT);
      while ((unsigned)(w >> 32) != t)
        w = __hip_atomic_load(pp, __ATOMIC_RELAXED, __HIP_MEMORY_SCOPE_AGENT);
      hs2[p][(tid >> 5) * 36 + (tid & 31)] = (unsigned)w;
    }
    __syncthreads();
    if (tid < 192 && t < 2048u) {
      const unsigned* hp0 = &hs2[p][(2 * piece) * 36];
      const unsigned* hp1 = &hs2[p][(2 * piece + 1) * 36];
      float a00 = 0.f, a01 = 0.f, a10 = 0.f, a11 = 0.f;
      #pragma unroll
      for (int i = 0; i < 8; ++i) {
        uint4 h4 = *(const uint4*)(hp0 + 4 * i);
        a00 = dot2f(w0r[4 * i + 0], h4.x, a00);
        a01 = dot2f(w0r[4 * i + 1], h4.y, a01);
        a00 = dot2f(w0r[4 * i + 2], h4.z, a00);
        a01 = dot2f(w0r[4 * i + 3], h4.w, a01);
        a10 = dot2f(w1r[4 * i + 0], h4.x, a10);
        a11 = dot2f(w1r[4 * i + 1], h4.y, a11);
        a10 = dot2f(w1r[4 * i + 2], h4.z, a10);
        a11 = dot2f(w1r[4 * i + 3], h4.w, a11);
      }
      #pragma unroll
      for (int i = 0; i < 8; ++i) {
        uint4 h4 = *(const uint4*)(hp1 + 4 * i);
        a00 = dot2f(w0r[32 + 4 * i + 0], h4.x, a00);
        a01 = dot2f(w0r[32 + 4 * i + 1], h4.y, a01);
        a00 = dot2f(w0r[32 + 4 * i + 2], h4.z, a00);
        a01 = dot2f(w0r[32 + 4 * i + 3], h4.w, a01);
        a10 = dot2f(w1r[32 + 4 * i + 0], h4.x, a10);
        a11 = dot2f(w1r[32 + 4 * i + 1], h4.y, a11);
        a10 = dot2f(w1r[32 + 4 * i + 2], h4.z, a10);
        a11 = dot2f(w1r[32 + 4 * i + 3], h4.w, a11);
      }
      red[p][(2 * rp) * 4 + piece]     = a00 + a01;
      red[p][(2 * rp + 1) * 4 + piece] = a10 + a11;
    }
    __syncthreads();
    if (tid < 32 && t < 2048u) {
      float4 q0 = *(const float4*)&red[p][tid * 4];
      float4 z0 = *(const float4*)&red[p][(32 + tid) * 4];
      float4 n0 = *(const float4*)&red[p][(64 + tid) * 4];
      float ghr = ((q0.x + q0.y) + (q0.z + q0.w)) + bhh_s[tid];
      float ghz = ((z0.x + z0.y) + (z0.z + z0.w)) + bhh_s[32 + tid];
      float ghn = ((n0.x + n0.y) + (n0.z + n0.w)) + bhh_s[64 + tid];
      float r  = fastrcp(1.0f + __expf(-(gir + ghr)));
      float zg = fastrcp(1.0f + __expf(-(giz + ghz)));
      float e2 = __expf(2.0f * (gin + r * ghn));
      float n  = 1.0f - 2.0f * fastrcp(e2 + 1.0f);
      float hnew = (1.0f - zg) * n + zg * hprev;
      hprev = hnew;
      float hpart = __shfl_xor(hnew, 1);
      if ((tid & 1) == 0) {
        union { unsigned u32; _Float16 hh[2]; } pk;
        pk.hh[0] = (_Float16)hnew;
        pk.hh[1] = (_Float16)hpart;
        unsigned long long wq = ((unsigned long long)(t + 1u) << 32) | (unsigned long long)pk.u32;
        __hip_atomic_store(hbuf + ((size_t)((t + 1u) & 1u) * 4 + b) * 256 + (u0 >> 1) + (tid >> 1),
                           wq, __ATOMIC_RELAXED, __HIP_MEMORY_SCOPE_AGENT);
      }
    }
    // ---- fused heads on wave 3, AFTER the store (hides in next poll window) ----
    // frame fr = t-1 when fr%16 == wgi; reads hs2[p] (= h_{t-1}), safe until step t+2.
    if (tid >= 192 && t >= 1u && (int)((t - 1u) & 15u) == wgi) {
      unsigned fr = t - 1u;
      int j = tid - 192;
      int pc = j & 3;
      const unsigned* hh0 = &hs2[p][(2 * pc) * 36];
      const unsigned* hh1 = &hs2[p][(2 * pc + 1) * 36];
      float a0 = 0.f, a1 = 0.f;
      #pragma unroll
      for (int i = 0; i < 8; ++i) {
        uint4 h4 = *(const uint4*)(hh0 + 4 * i);
        a0 = dot2f(w0r[4 * i + 0], h4.x, a0);
        a1 = dot2f(w0r[4 * i + 1], h4.y, a1);
        a0 = dot2f(w0r[4 * i + 2], h4.z, a0);
        a1 = dot2f(w0r[4 * i + 3], h4.w, a1);
      }
      #pragma unroll
      for (int i = 0; i < 8; ++i) {
        uint4 h4 = *(const uint4*)(hh1 + 4 * i);
        a0 = dot2f(w0r[32 + 4 * i + 0], h4.x, a0);
        a1 = dot2f(w0r[32 + 4 * i + 1], h4.y, a1);
        a0 = dot2f(w0r[32 + 4 * i + 2], h4.z, a0);
        a1 = dot2f(w0r[32 + 4 * i + 3], h4.w, a1);
      }
      float vs = a0 + a1;
      vs += __shfl_xor(vs, 1);
      vs += __shfl_xor(vs, 2);     // all 4 lanes of a quad hold the head sum
      float s0 = __shfl(vs, 0),  s1 = __shfl(vs, 4),  s2 = __shfl(vs, 8);
      float s3 = __shfl(vs, 12), s4 = __shfl(vs, 16), s5 = __shfl(vs, 20);
      float s6 = __shfl(vs, 24), s7 = __shfl(vs, 28), s8 = __shfl(vs, 32);
      float s9 = __shfl(vs, 36), s10 = __shfl(vs, 40);
      if (j == 0) {
        size_t bf = (size_t)b * 2048 + fr;
        float oqv = fastrcp(1.0f + __expf(-(s0 + hb0)));
        float vg = fastsoftplus(s1 + hb1);
        float ug = fastsoftplus(s2 + hb2);
        out[O1 + bf] = oqv; oqw[bf] = oqv;
        out[O2 + bf] = vg;  vgw[bf] = vg;
        out[O3 + bf] = ug;  ugw[bf] = ug;
        float run = 200.0f;
        run += fastsoftplus(s3 + hbf0); out[O4 + bf * 4 + 0] = run; ffw[bf * 4 + 0] = run;
        run += fastsoftplus(s4 + hbf1); out[O4 + bf * 4 + 1] = run; ffw[bf * 4 + 1] = run;
        run += fastsoftplus(s5 + hbf2); out[O4 + bf * 4 + 2] = run; ffw[bf * 4 + 2] = run;
        run += fastsoftplus(s6 + hbf3); out[O4 + bf * 4 + 3] = run; ffw[bf * 4 + 3] = run;
        float g0 = fastsoftplus(s7 + hbb0) + 50.0f;  out[O5 + bf * 4 + 0] = g0; fbw[bf * 4 + 0] = g0;
        float g1 = fastsoftplus(s8 + hbb1) + 50.0f;  out[O5 + bf * 4 + 1] = g1; fbw[bf * 4 + 1] = g1;
        float g2 = fastsoftplus(s9 + hbb2) + 50.0f;  out[O5 + bf * 4 + 2] = g2; fbw[bf * 4 + 2] = g2;
        float g3 = fastsoftplus(s10 + hbb3) + 50.0f; out[O5 + bf * 4 + 3] = g3; fbw[bf * 4 + 3] = g3;
      }
    }
  }
}

// ---------------- per-batch prefix scan of cycles -> start phase ----------------
__global__ __launch_bounds__(256) void k_scan(const float* __restrict__ f0, float* __restrict__ startw) {
  __shared__ float ts[256];
  int b = blockIdx.x, tid = threadIdx.x;
  const float CY = 256.0f / 24000.0f;
  float c[8], run = 0.f;
  int base = b * 2048 + tid * 8;
  #pragma unroll
  for (int j = 0; j < 8; ++j) { c[j] = run; run += f0[base + j] * CY; }
  ts[tid] = run;
  __syncthreads();
  for (int off = 1; off < 256; off <<= 1) {
    float v = (tid >= off) ? ts[tid - off] : 0.0f;
    __syncthreads();
    ts[tid] += v;
    __syncthreads();
  }
  float excl = (tid == 0) ? 0.0f : ts[tid - 1];
  #pragma unroll
  for (int j = 0; j < 8; ++j) {
    float st = excl + c[j];
    startw[base + j] = st - floorf(st);
  }
}

// ---------------- fused synth: excitation + formant IR + conv/OLA ----------------
// fast-math trig: __sinf/__cosf/__expf (args <= ~64 revolutions, err ~1e-4 << f16 path)
__global__ __launch_bounds__(256) void k_synth(
    const float* __restrict__ f0, const float* __restrict__ noise,
    const float* __restrict__ startw, const float* __restrict__ oqw,
    const float* __restrict__ vgw, const float* __restrict__ ugw,
    const float* __restrict__ ffw, const float* __restrict__ fbw,
    float* __restrict__ audio)
{
  __shared__ float es[256];
  __shared__ float fp[1536];
  __shared__ float ffs[4], fbs[4], ssc[1], wmax[4];
  int bf = blockIdx.x, tid = threadIdx.x;
  int b = bf >> 11, f = bf & 2047;

  // excitation -> es
  {
    float st = startw[bf], f0v = f0[bf], oqv = oqw[bf], vg = vgw[bf], ug = ugw[bf];
    float total = st + f0v * ((float)tid * (1.0f / 24000.0f));
    float phi = total - floorf(total);
    float peak = oqv * 0.66f;
    float rise = 0.5f * (1.0f - __cosf(PI_F * phi / (peak + 1e-6f)));
    float fall = __cosf(PI_F * (phi - peak) / (2.0f * (oqv - peak) + 1e-6f));
    float v = (phi < peak) ? rise : ((phi < oqv) ? fall : 0.0f);
    es[tid] = v * vg + noise[(size_t)bf * 256 + tid] * ug;
  }
  if (tid < 4) { ffs[tid] = ffw[(size_t)bf * 4 + tid]; fbs[tid] = fbw[(size_t)bf * 4 + tid]; }
  fp[tid] = 0.0f;          // fp[0..255]
  fp[1280 + tid] = 0.0f;   // fp[1280..1535]
  __syncthreads();

  // formant IR + normalization -> fp[256..1279] reversed
  float vals[4];
  float am = 0.f;
  #pragma unroll
  for (int it = 0; it < 4; ++it) {
    int k = it * 256 + tid;
    float t = (float)k * (1.0f / 24000.0f);
    float s = 0.f;
    #pragma unroll
    for (int j = 0; j < 4; ++j)
      s += __expf(-PI_F * fbs[j] * t) * __sinf(TWO_PI_F * ffs[j] * t);
    vals[it] = s;
    am = fmaxf(am, fabsf(s));
  }
  #pragma unroll
  for (int m = 1; m < 64; m <<= 1) am = fmaxf(am, __shfl_xor(am, m));
  if ((tid & 63) == 0) wmax[tid >> 6] = am;
  __syncthreads();
  if (tid == 0) ssc[0] = fmaxf(fmaxf(wmax[0], wmax[1]), fmaxf(wmax[2], wmax[3])) + 1e-8f;
  __syncthreads();
  float inv = 1.0f / ssc[0];
  #pragma unroll
  for (int it = 0; it < 4; ++it) {
    int k = it * 256 + tid;
    fp[256 + (1023 - k)] = vals[it] * inv;
  }
  __syncthreads();

  // conv (full) + overlap-add
  int n0 = tid * 5;
  float V0 = fp[n0 + 256], V1 = fp[n0 + 257], V2 = fp[n0 + 258], V3 = fp[n0 + 259], V4 = fp[n0 + 260];
  float a0 = 0.f, a1 = 0.f, a2 = 0.f, a3 = 0.f, a4 = 0.f;
  #pragma unroll 4
  for (int m = 0; m < 256; ++m) {
    float e = es[m];
    a0 = fmaf(e, V0, a0); a1 = fmaf(e, V1, a1); a2 = fmaf(e, V2, a2);
    a3 = fmaf(e, V3, a3); a4 = fmaf(e, V4, a4);
    V4 = V3; V3 = V2; V2 = V1; V1 = V0;
    V0 = fp[n0 + 255 - m];
  }
  float* arow = audio + (size_t)b * AROW + APAD + (size_t)f * 256;
  if (n0 + 0 < LL) atomicAdd(&arow[n0 + 0], a0);
  if (n0 + 1 < LL) atomicAdd(&arow[n0 + 1], a1);
  if (n0 + 2 < LL) atomicAdd(&arow[n0 + 2], a2);
  if (n0 + 3 < LL) atomicAdd(&arow[n0 + 3], a3);
  if (n0 + 4 < LL) atomicAdd(&arow[n0 + 4], a4);
}

// ---------------- pack audio fp32 -> f16 halves (row stride AROW2, zero tail pad) ----------------
__global__ __launch_bounds__(256) void k_packaudio(const float* __restrict__ audio,
                                                   unsigned* __restrict__ af) {
  int idx = blockIdx.x * 256 + threadIdx.x;   // dword index (2 halves)
  int b = blockIdx.y;
  size_t i0 = (size_t)idx * 2;
  if (i0 < AROW2) {
    float a = (i0 < AROW)     ? audio[(size_t)b * AROW + i0]     : 0.0f;
    float c = (i0 + 1 < AROW) ? audio[(size_t)b * AROW + i0 + 1] : 0.0f;
    union { unsigned u32; _Float16 h[2]; } pk;
    pk.h[0] = (_Float16)a; pk.h[1] = (_Float16)c;
    af[(size_t)b * (AROW2 / 2) + idx] = pk.u32;
  }
}

// ---------------- Toeplitz IR fragments for MFMA reverb ----------------
// W_p[r][k] = ir[32p + 16 + r - k], r in [0,16), k in [0,32), zero outside [0,REV).
// Fragment layout (= working k_gemm_gi A-operand): lane l holds r = l&15,
// k = (l>>4)*8 + i for i in 0..7, packed as 4 dwords (h[2j] = low half of dword j).
__global__ __launch_bounds__(256) void k_wtaps(const float* __restrict__ ir, uint4* __restrict__ wtap) {
  int g = blockIdx.x * 256 + threadIdx.x;
  int p = g >> 6, l = g & 63;
  if (p < 752) {
    int base = 32 * p + 16 + (l & 15) - ((l >> 4) << 3);
    unsigned dw[4];
    #pragma unroll
    for (int j = 0; j < 4; ++j) {
      int i0 = base - 2 * j, i1 = base - 2 * j - 1;
      float v0 = (i0 >= 0 && i0 < REV) ? ir[i0] : 0.0f;
      float v1 = (i1 >= 0 && i1 < REV) ? ir[i1] : 0.0f;
      union { unsigned u32; _Float16 h[2]; } pk;
      pk.h[0] = (_Float16)v0; pk.h[1] = (_Float16)v1;
      dw[j] = pk.u32;
    }
    uint4 o; o.x = dw[0]; o.y = dw[1]; o.z = dw[2]; o.w = dw[3];
    wtap[(size_t)(p << 6) + l] = o;
  }
}

// ---------------- reverb v6: block-Toeplitz MFMA conv ----------------
constexpr int PC = 16;       // tap-pairs per chunk
constexpr int NCHUNK = 47;   // covers p 0..751 (752 padded with zeros)
constexpr int WINH = 2544;   // window halves: 32*(PC-1) + 2064

__global__ __launch_bounds__(256) void k_reverb(
    const float* __restrict__ audio, const unsigned short* __restrict__ af,
    const uint4* __restrict__ wtap, const float* __restrict__ wetl,
    float* __restrict__ out)
{
  __shared__ __align__(16) unsigned short win[WINH];
  __shared__ uint4 wlds[PC * 64];
  int tb = blockIdx.x, b = blockIdx.y, tid = threadIdx.x;
  const int wv = tid >> 6, lane = tid & 63;
  const int lm = lane & 15, quad = lane >> 4;
  int q0 = tb * 128;
  const unsigned short* afrow = af + (size_t)b * AROW2;
  f32x4 acc0 = {0.f,0.f,0.f,0.f}, acc1 = {0.f,0.f,0.f,0.f};

  for (int c = 0; c < NCHUNK; ++c) {
    int p0 = c * PC;
    int b_lo = 16 * q0 - 32 * (p0 + PC - 1) - 16;        // >= -24048; APAD covers it
    const uint4* src = (const uint4*)(afrow + (APAD + b_lo));
    __syncthreads();
    for (int u = tid; u < 318 + PC * 64; u += 256) {
      if (u < 318) ((uint4*)win)[u] = src[u];
      else         wlds[u - 318] = wtap[(size_t)p0 * 64 + (u - 318)];
    }
    __syncthreads();
    int offb = 16 * lm + 8 * quad;
    int tA = (2 * wv) * 256 + offb, tB = (2 * wv + 1) * 256 + offb;
    #pragma unroll 4
    for (int pl = 0; pl < PC; ++pl) {
      union { uint4 u; f16x8 h; } wf, b0, b1;
      wf.u = wlds[pl * 64 + lane];
      int offp = 32 * (PC - 1 - pl);
      b0.u = *(const uint4*)&win[offp + tA];
      b1.u = *(const uint4*)&win[offp + tB];
      acc0 = __builtin_amdgcn_mfma_f32_16x16x32_f16(wf.h, b0.h, acc0, 0, 0, 0);
      acc1 = __builtin_amdgcn_mfma_f32_16x16x32_f16(wf.h, b1.h, acc1, 0, 0, 0);
    }
  }
  float wet = sigmoidf_(wetl[0]);
  const float* arow = audio + (size_t)b * AROW;
  #pragma unroll
  for (int tile = 0; tile < 2; ++tile) {
    const f32x4& ac = tile ? acc1 : acc0;
    int qt = q0 + (2 * wv + tile) * 16 + lm;
    #pragma unroll
    for (int rg = 0; rg < 4; ++rg) {
      long t = (long)16 * qt + quad * 4 + rg;
      if (t < (long)TOT) {
        float av = arow[APAD + t];
        out[(size_t)b * TOT + t] = (1.0f - wet) * av + wet * ac[rg];
      }
    }
  }
}

// ---------------- launch ----------------
extern "C" void kernel_launch(void* const* d_in, const int* in_sizes, int n_in,
                              void* d_out, int out_size, void* d_ws, size_t ws_size,
                              hipStream_t stream) {
  const float* f0       = (const float*)d_in[0];
  const float* loud     = (const float*)d_in[1];
  const float* gender   = (const float*)d_in[2];
  const float* age      = (const float*)d_in[3];
  const float* z        = (const float*)d_in[4];
  const float* noise    = (const float*)d_in[5];
  const float* W_in     = (const float*)d_in[6];
  const float* b_in     = (const float*)d_in[7];
  const float* W_ih     = (const float*)d_in[8];
  const float* W_hh     = (const float*)d_in[9];
  const float* b_ih     = (const float*)d_in[10];
  const float* b_hh     = (const float*)d_in[11];
  const float* W_oq     = (const float*)d_in[12];
  const float* b_oq     = (const float*)d_in[13];
  const float* W_vg     = (const float*)d_in[14];
  const float* b_vg     = (const float*)d_in[15];
  const float* W_ug     = (const float*)d_in[16];
  const float* b_ug     = (const float*)d_in[17];
  const float* W_ff     = (const float*)d_in[18];
  const float* b_ff     = (const float*)d_in[19];
  const float* W_fb     = (const float*)d_in[20];
  const float* b_fb     = (const float*)d_in[21];
  const float* rev_ir   = (const float*)d_in[22];
  const float* wet_l    = (const float*)d_in[23];

  float* out = (float*)d_out;
  char* ws = (char*)d_ws;
  float* x      = (float*)(ws + OFF_X);
  float* gi     = (float*)(ws + OFF_GI);
  float* oqw    = (float*)(ws + OFF_OQ);
  float* vgw    = (float*)(ws + OFF_VG);
  float* ugw    = (float*)(ws + OFF_UG);
  float* ffw    = (float*)(ws + OFF_FFW);
  float* fbw    = (float*)(ws + OFF_FBW);
  float* startw = (float*)(ws + OFF_START);
  float* f0m    = (float*)(ws + OFF_F0M);
  unsigned long long* hbuf = (unsigned long long*)(ws + OFF_HBUF);
  uint4* wtap   = (uint4*)(ws + OFF_WTAP);
  unsigned* af  = (unsigned*)(ws + OFF_AF16);
  float* audio  = (float*)(ws + OFF_AUDIO);

  // zero tagged h double-buffer (16KB, own region) + audio acc
  hipMemsetAsync(ws + OFF_HBUF, 0, 16384, stream);
  hipMemsetAsync(ws + OFF_AUDIO, 0, (size_t)4 * AROW * 4, stream);

  k_f0mean<<<4, 256, 0, stream>>>(f0, f0m);
  k_inproj<<<512, 256, 0, stream>>>(f0, loud, gender, age, z, f0m, W_in, b_in, x);
  k_gemm_gi<<<dim3(24, 128), 256, 0, stream>>>(x, W_ih, b_ih, gi);
  k_gru<<<64, 256, 0, stream>>>(W_hh, b_hh, gi, hbuf,
                                W_oq, b_oq, W_vg, b_vg, W_ug, b_ug,
                                W_ff, b_ff, W_fb, b_fb,
                                out, oqw, vgw, ugw, ffw, fbw);
  k_scan<<<4, 256, 0, stream>>>(f0, startw);
  k_wtaps<<<188, 256, 0, stream>>>(rev_ir, wtap);      // gi region dead after k_gru
  k_synth<<<8192, 256, 0, stream>>>(f0, noise, startw, oqw, vgw, ugw, ffw, fbw, audio);
  k_packaudio<<<dim3(1077, 4), 256, 0, stream>>>(audio, af);  // x region dead after gemm
  k_reverb<<<dim3(257, 4), 256, 0, stream>>>(audio, (const unsigned short*)af, wtap, wet_l, out);
}

// Round 11
// 3171.516 us; speedup vs baseline: 1.2287x; 1.0580x over previous
//
#include <hip/hip_runtime.h>
#include <hip/hip_bf16.h>
#include <math.h>

// ---------------- constants ----------------
#define PI_F 3.14159265358979323846f
#define TWO_PI_F 6.283185307179586f

constexpr int BB = 4;            // batch
constexpr int FF_ = 2048;        // frames
constexpr int RC = 512;          // rnn channels
constexpr int HOP = 256;
constexpr int KK = 1024;         // FIR len
constexpr int LL = HOP + KK - 1; // 1279
constexpr size_t TOT = 525311;   // (F-1)*HOP + L
constexpr int APAD = 24064;      // zero pad in front of audio rows (>= REV-1, mult of 64)
constexpr size_t AROW = 549376;  // APAD + 525312
constexpr int REV = 24000;
constexpr size_t AROW2 = 551424; // af16 row halves: AROW + 2048 tail pad

// output offsets (floats)
constexpr size_t O1 = 2101244;   // oq
constexpr size_t O2 = 2109436;   // v_gain
constexpr size_t O3 = 2117628;   // u_gain
constexpr size_t O4 = 2125820;   // ff
constexpr size_t O5 = 2158588;   // fb

// workspace offsets (bytes)
// R10 FIX: R9 put wtap at 50331648 — INSIDE gi [16777216,67108864), which k_gru reads
// while the co-resident wtaps WGs write -> corrupted gates (absmax 236). wtap now lives
// in the old x region (x dead after k_gemm_gi, before k_gru): [8388608, 9158656).
// af16 later reuses only [0, 4411392) of that region -> no overlap with wtap or k_reverb.
constexpr size_t OFF_X      = 0;                 // 8192*512*4 ; af16 reuses [0,4.41MB) after gemm
constexpr size_t OFF_WTAP   = 8388608;           // Toeplitz IR MFMA fragments (770048B) — x dead-zone
constexpr size_t OFF_GI     = 16777216;          // 8192*1536*4
constexpr size_t OFF_HS     = 67108864;          // 8192*512*4
constexpr size_t OFF_OQ     = 83886080;
constexpr size_t OFF_VG     = 83918848;
constexpr size_t OFF_UG     = 83951616;
constexpr size_t OFF_FFW    = 83984384;          // also hbuf (16KB) during k_gru; ffw written after
constexpr size_t OFF_FBW    = 84115456;
constexpr size_t OFF_START  = 84246528;
constexpr size_t OFF_F0M    = 84279296;
constexpr size_t OFF_AUDIO  = 92684800;          // 4*549376*4
constexpr size_t OFF_AF16   = OFF_X;             // packed f16 audio, 4*551424*2 = 4.41MB

constexpr size_t OFF_HBUF   = OFF_FFW;           // 2 slots x 4 batch x 256 words x 8B = 16KB

__device__ __forceinline__ float softplusf(float x) {
  return x > 20.0f ? x : log1pf(expf(x));
}
__device__ __forceinline__ float sigmoidf_(float x) {
  return 1.0f / (1.0f + expf(-x));
}
__device__ __forceinline__ float fastrcp(float x) {
#if __has_builtin(__builtin_amdgcn_rcpf)
  return __builtin_amdgcn_rcpf(x);
#else
  return 1.0f / x;
#endif
}

typedef _Float16 half2v __attribute__((ext_vector_type(2)));
typedef _Float16 f16x8 __attribute__((ext_vector_type(8)));
typedef float f32x4 __attribute__((ext_vector_type(4)));

__device__ __forceinline__ float dot2f(unsigned wa, unsigned hb, float acc) {
#if __has_builtin(__builtin_amdgcn_fdot2)
  union { unsigned u; half2v h; } A, B;
  A.u = wa; B.u = hb;
  return __builtin_amdgcn_fdot2(A.h, B.h, acc, false);
#else
  union { unsigned u; _Float16 h[2]; } A, B;
  A.u = wa; B.u = hb;
  return fmaf((float)A.h[0], (float)B.h[0], fmaf((float)A.h[1], (float)B.h[1], acc));
#endif
}

// ---------------- f0 mean per batch ----------------
__global__ __launch_bounds__(256) void k_f0mean(const float* __restrict__ f0, float* __restrict__ f0m) {
  int b = blockIdx.x, tid = threadIdx.x;
  float s = 0.f;
  for (int t = tid; t < FF_; t += 256) s += f0[b*FF_ + t];
  #pragma unroll
  for (int m = 1; m < 64; m <<= 1) s += __shfl_xor(s, m);
  __shared__ float ws4[4];
  if ((tid & 63) == 0) ws4[tid >> 6] = s;
  __syncthreads();
  if (tid == 0) f0m[b] = (ws4[0] + ws4[1] + ws4[2] + ws4[3]) * (1.0f / 2048.0f);
}

// ---------------- input projection: x = relu(concat @ W_in^T + b_in) ----------------
__global__ __launch_bounds__(256) void k_inproj(
    const float* __restrict__ f0, const float* __restrict__ loud,
    const float* __restrict__ gender, const float* __restrict__ age,
    const float* __restrict__ z, const float* __restrict__ f0m,
    const float* __restrict__ Win, const float* __restrict__ bin,
    float* __restrict__ x)
{
  __shared__ float inp[16 * 28];
  int r0 = blockIdx.x * 16;   // bf base
  int tid = threadIdx.x;
  for (int i = tid; i < 16 * 28; i += 256) {
    int r = i / 28, c = i % 28;
    int bf = r0 + r, b = bf >> 11;
    float v;
    if (c == 0)       v = f0[bf] - f0m[b];
    else if (c == 1)  v = loud[bf];
    else if (c < 4)   v = gender[(size_t)bf*2 + (c - 2)];
    else if (c < 12)  v = age[(size_t)bf*8 + (c - 4)];
    else              v = z[(size_t)bf*16 + (c - 12)];
    inp[i] = v;
  }
  __syncthreads();
  for (int o = tid; o < 16 * 512; o += 256) {
    int r = o >> 9, j = o & 511;
    const float* w = Win + j * 28;
    const float* ip = inp + r * 28;
    float a = bin[j];
    #pragma unroll
    for (int c2 = 0; c2 < 28; ++c2) a = fmaf(w[c2], ip[c2], a);
    x[(size_t)(r0 + r) * 512 + j] = fmaxf(a, 0.0f);
  }
}

// ---------------- GEMM v2 (MFMA f16): gi = x @ W_ih^T + b_ih ----------------
__global__ __launch_bounds__(256) void k_gemm_gi(
    const float* __restrict__ A, const float* __restrict__ Bw,
    const float* __restrict__ bias, float* __restrict__ C)
{
  __shared__ unsigned As[64 * 20];  // f16-pair dwords, row stride 20
  __shared__ unsigned Bs[64 * 20];
  int tid = threadIdx.x;
  int n0 = blockIdx.x * 64, m0 = blockIdx.y * 64;
  const int w = tid >> 6;           // wave 0..3
  const int lane = tid & 63;
  const int mrow0 = (w >> 1) * 32;
  const int ncol0 = (w & 1) * 32;
  const int lm = lane & 15;
  const int quad = lane >> 4;

  f32x4 acc00 = {0.f,0.f,0.f,0.f}, acc01 = {0.f,0.f,0.f,0.f};
  f32x4 acc10 = {0.f,0.f,0.f,0.f}, acc11 = {0.f,0.f,0.f,0.f};

  for (int k0 = 0; k0 < 512; k0 += 32) {
    __syncthreads();
    for (int i = tid; i < 1024; i += 256) {
      int r = i >> 4, d = i & 15;
      float2 av = *(const float2*)(A + (size_t)(m0 + r) * 512 + k0 + 2 * d);
      float2 bv = *(const float2*)(Bw + (size_t)(n0 + r) * 512 + k0 + 2 * d);
      union { unsigned u32; _Float16 h[2]; } pa, pb;
      pa.h[0] = (_Float16)av.x; pa.h[1] = (_Float16)av.y;
      pb.h[0] = (_Float16)bv.x; pb.h[1] = (_Float16)bv.y;
      As[r * 20 + d] = pa.u32;
      Bs[r * 20 + d] = pb.u32;
    }
    __syncthreads();
    union { uint4 u; f16x8 h; } a0, a1, b0, b1;
    a0.u = *(const uint4*)&As[(mrow0 + lm) * 20 + quad * 4];
    a1.u = *(const uint4*)&As[(mrow0 + 16 + lm) * 20 + quad * 4];
    b0.u = *(const uint4*)&Bs[(ncol0 + lm) * 20 + quad * 4];
    b1.u = *(const uint4*)&Bs[(ncol0 + 16 + lm) * 20 + quad * 4];
    acc00 = __builtin_amdgcn_mfma_f32_16x16x32_f16(a0.h, b0.h, acc00, 0, 0, 0);
    acc01 = __builtin_amdgcn_mfma_f32_16x16x32_f16(a0.h, b1.h, acc01, 0, 0, 0);
    acc10 = __builtin_amdgcn_mfma_f32_16x16x32_f16(a1.h, b0.h, acc10, 0, 0, 0);
    acc11 = __builtin_amdgcn_mfma_f32_16x16x32_f16(a1.h, b1.h, acc11, 0, 0, 0);
  }
  #pragma unroll
  for (int sm = 0; sm < 2; ++sm) {
    #pragma unroll
    for (int sn = 0; sn < 2; ++sn) {
      const f32x4& ac = sm ? (sn ? acc11 : acc10) : (sn ? acc01 : acc00);
      int col = n0 + ncol0 + sn * 16 + lm;
      float bb = bias[col];
      #pragma unroll
      for (int rg = 0; rg < 4; ++rg) {
        int row = m0 + mrow0 + sm * 16 + quad * 4 + rg;
        C[(size_t)row * 1536 + col] = ac[rg] + bb;
      }
    }
  }
}

// ---------------- persistent GRU v15b: exact v11 (R5, 2650us) + co-resident scan/wtaps WGs ----------------
// GRU structure byte-identical to v11 (best measured). Extra work goes to EXTRA WGs (R7/R8
// lesson: work added inside gru WGs lands on the critical path). bid 0..63: gru. bid 64..67:
// k_scan body. bid 68..255: k_wtaps body (wtap now in x dead-zone — R9's bug was wtap
// overwriting live gi). scan/wtaps never touch hbuf/gi/hs; they retire in ~10us on
// otherwise-idle CUs while gru spins.
__global__ __launch_bounds__(256, 1) void k_gru(
    const float* __restrict__ Whh, const float* __restrict__ bhh,
    const float* __restrict__ gi, float* __restrict__ hs,
    unsigned long long* hbuf,
    const float* __restrict__ f0, float* __restrict__ startw,
    const float* __restrict__ ir, uint4* __restrict__ wtap)
{
  const int tid = threadIdx.x;
  const int bid = blockIdx.x;

  if (bid >= 64) {
    int xb = bid - 64;
    if (xb < 4) {
      // ---- k_scan body: per-batch prefix scan of cycles -> start phase ----
      __shared__ float ts[256];
      int b = xb;
      const float CY = 256.0f / 24000.0f;
      float c[8], run = 0.f;
      int base = b * 2048 + tid * 8;
      #pragma unroll
      for (int j = 0; j < 8; ++j) { c[j] = run; run += f0[base + j] * CY; }
      ts[tid] = run;
      __syncthreads();
      for (int off = 1; off < 256; off <<= 1) {
        float v = (tid >= off) ? ts[tid - off] : 0.0f;
        __syncthreads();
        ts[tid] += v;
        __syncthreads();
      }
      float excl = (tid == 0) ? 0.0f : ts[tid - 1];
      #pragma unroll
      for (int j = 0; j < 8; ++j) {
        float st = excl + c[j];
        startw[base + j] = st - floorf(st);
      }
    } else {
      // ---- k_wtaps body: Toeplitz IR MFMA fragments ----
      // W_p[r][k] = ir[32p+16+r-k]; lane l holds r=l&15, k=(l>>4)*8+i (k_gemm_gi A layout).
      int g = (xb - 4) * 256 + tid;
      int p = g >> 6, l = g & 63;
      if (p < 752) {
        int base = 32 * p + 16 + (l & 15) - ((l >> 4) << 3);
        unsigned dw[4];
        #pragma unroll
        for (int j = 0; j < 4; ++j) {
          int i0 = base - 2 * j, i1 = base - 2 * j - 1;
          float v0 = (i0 >= 0 && i0 < REV) ? ir[i0] : 0.0f;
          float v1 = (i1 >= 0 && i1 < REV) ? ir[i1] : 0.0f;
          union { unsigned u32; _Float16 h[2]; } pk;
          pk.h[0] = (_Float16)v0; pk.h[1] = (_Float16)v1;
          dw[j] = pk.u32;
        }
        uint4 o; o.x = dw[0]; o.y = dw[1]; o.z = dw[2]; o.w = dw[3];
        wtap[(size_t)(p << 6) + l] = o;
      }
    }
    return;
  }

  __shared__ unsigned hs2[2][292];   // 8 chunks x 36-dword stride per parity
  __shared__ float red[2][384];      // [row*4 + piece], 96 rows
  __shared__ float bhh_s[96];

  const int b   = (bid & 7) >> 1;                    // batch -> XCD pair {2b,2b+1}
  const int wgi = ((bid >> 3) << 1) | (bid & 1);     // 0..15
  const int u0  = wgi * 32;
  const int piece = tid & 3;         // 128-dim piece (dot threads tid<192)
  const int rp    = tid >> 2;        // row pair 0..47

  unsigned w0r[64], w1r[64];
  if (tid < 192) {
    int r0 = 2 * rp, r1 = 2 * rp + 1;                // rows 0..95 = gate*32 + unit
    const float* s0 = Whh + (size_t)((r0 >> 5) * 512 + u0 + (r0 & 31)) * 512 + piece * 128;
    const float* s1 = Whh + (size_t)((r1 >> 5) * 512 + u0 + (r1 & 31)) * 512 + piece * 128;
    #pragma unroll
    for (int j = 0; j < 64; ++j) {
      float2 a = *(const float2*)(s0 + 2 * j);
      float2 c = *(const float2*)(s1 + 2 * j);
      union { unsigned u32; _Float16 hh[2]; } ca, cb;
      ca.hh[0] = (_Float16)a.x; ca.hh[1] = (_Float16)a.y;
      cb.hh[0] = (_Float16)c.x; cb.hh[1] = (_Float16)c.y;
      w0r[j] = ca.u32; w1r[j] = cb.u32;
    }
  } else {
    #pragma unroll
    for (int j = 0; j < 64; ++j) { w0r[j] = 0u; w1r[j] = 0u; }
  }
  if (tid < 96) bhh_s[tid] = bhh[(tid >> 5) * 512 + u0 + (tid & 31)];
  __syncthreads();

  float hprev = 0.0f;

  #pragma unroll 1
  for (unsigned t = 0; t < 2048; ++t) {
    const int p = (int)(t & 1u);
    float gir = 0.f, giz = 0.f, gin = 0.f;
    if (tid < 32) {
      const float* gp = gi + (size_t)(b * 2048 + (int)t) * 1536 + u0 + tid;
      gir = gp[0]; giz = gp[512]; gin = gp[1024];
    }
    {
      const unsigned long long* pp = hbuf + ((size_t)p * 4 + b) * 256 + tid;
      unsigned long long w = __hip_atomic_load(pp, __ATOMIC_RELAXED, __HIP_MEMORY_SCOPE_AGENT);
      while ((unsigned)(w >> 32) != t)
        w = __hip_atomic_load(pp, __ATOMIC_RELAXED, __HIP_MEMORY_SCOPE_AGENT);
      hs2[p][(tid >> 5) * 36 + (tid & 31)] = (unsigned)w;
    }
    __syncthreads();
    if (tid < 192) {
      const unsigned* hp0 = &hs2[p][(2 * piece) * 36];
      const unsigned* hp1 = &hs2[p][(2 * piece + 1) * 36];
      float a00 = 0.f, a01 = 0.f, a10 = 0.f, a11 = 0.f;
      #pragma unroll
      for (int i = 0; i < 8; ++i) {
        uint4 h4 = *(const uint4*)(hp0 + 4 * i);
        a00 = dot2f(w0r[4 * i + 0], h4.x, a00);
        a01 = dot2f(w0r[4 * i + 1], h4.y, a01);
        a00 = dot2f(w0r[4 * i + 2], h4.z, a00);
        a01 = dot2f(w0r[4 * i + 3], h4.w, a01);
        a10 = dot2f(w1r[4 * i + 0], h4.x, a10);
        a11 = dot2f(w1r[4 * i + 1], h4.y, a11);
        a10 = dot2f(w1r[4 * i + 2], h4.z, a10);
        a11 = dot2f(w1r[4 * i + 3], h4.w, a11);
      }
      #pragma unroll
      for (int i = 0; i < 8; ++i) {
        uint4 h4 = *(const uint4*)(hp1 + 4 * i);
        a00 = dot2f(w0r[32 + 4 * i + 0], h4.x, a00);
        a01 = dot2f(w0r[32 + 4 * i + 1], h4.y, a01);
        a00 = dot2f(w0r[32 + 4 * i + 2], h4.z, a00);
        a01 = dot2f(w0r[32 + 4 * i + 3], h4.w, a01);
        a10 = dot2f(w1r[32 + 4 * i + 0], h4.x, a10);
        a11 = dot2f(w1r[32 + 4 * i + 1], h4.y, a11);
        a10 = dot2f(w1r[32 + 4 * i + 2], h4.z, a10);
        a11 = dot2f(w1r[32 + 4 * i + 3], h4.w, a11);
      }
      red[p][(2 * rp) * 4 + piece]     = a00 + a01;
      red[p][(2 * rp + 1) * 4 + piece] = a10 + a11;
    }
    __syncthreads();
    if (tid < 32) {
      float4 q0 = *(const float4*)&red[p][tid * 4];
      float4 z0 = *(const float4*)&red[p][(32 + tid) * 4];
      float4 n0 = *(const float4*)&red[p][(64 + tid) * 4];
      float ghr = ((q0.x + q0.y) + (q0.z + q0.w)) + bhh_s[tid];
      float ghz = ((z0.x + z0.y) + (z0.z + z0.w)) + bhh_s[32 + tid];
      float ghn = ((n0.x + n0.y) + (n0.z + n0.w)) + bhh_s[64 + tid];
      float r  = fastrcp(1.0f + __expf(-(gir + ghr)));
      float zg = fastrcp(1.0f + __expf(-(giz + ghz)));
      float e2 = __expf(2.0f * (gin + r * ghn));
      float n  = 1.0f - 2.0f * fastrcp(e2 + 1.0f);
      float hnew = (1.0f - zg) * n + zg * hprev;
      hprev = hnew;
      float hpart = __shfl_xor(hnew, 1);
      if ((tid & 1) == 0) {
        union { unsigned u32; _Float16 hh[2]; } pk;
        pk.hh[0] = (_Float16)hnew;
        pk.hh[1] = (_Float16)hpart;
        unsigned long long wq = ((unsigned long long)(t + 1u) << 32) | (unsigned long long)pk.u32;
        __hip_atomic_store(hbuf + ((size_t)((t + 1u) & 1u) * 4 + b) * 256 + (u0 >> 1) + (tid >> 1),
                           wq, __ATOMIC_RELAXED, __HIP_MEMORY_SCOPE_AGENT);
      }
      hs[(size_t)(b * 2048 + (int)t) * 512 + u0 + tid] = hnew;
    }
  }
}

// ---------------- heads: oq, v_gain, u_gain, ff(cumsum), fb ----------------
__global__ __launch_bounds__(256) void k_heads(
    const float* __restrict__ hs,
    const float* __restrict__ Woq, const float* __restrict__ boq,
    const float* __restrict__ Wvg, const float* __restrict__ bvg,
    const float* __restrict__ Wug, const float* __restrict__ bug,
    const float* __restrict__ Wff, const float* __restrict__ bff,
    const float* __restrict__ Wfb, const float* __restrict__ bfb,
    float* __restrict__ out,
    float* __restrict__ oqw, float* __restrict__ vgw, float* __restrict__ ugw,
    float* __restrict__ ffw, float* __restrict__ fbw)
{
  int bf = blockIdx.x, tid = threadIdx.x;
  const float* h = hs + (size_t)bf * 512;
  float p[11];
  #pragma unroll
  for (int i = 0; i < 11; ++i) p[i] = 0.f;
  for (int k = tid; k < 512; k += 256) {
    float hv = h[k];
    p[0] = fmaf(Woq[k], hv, p[0]);
    p[1] = fmaf(Wvg[k], hv, p[1]);
    p[2] = fmaf(Wug[k], hv, p[2]);
    p[3] = fmaf(Wff[k], hv, p[3]);
    p[4] = fmaf(Wff[512 + k], hv, p[4]);
    p[5] = fmaf(Wff[1024 + k], hv, p[5]);
    p[6] = fmaf(Wff[1536 + k], hv, p[6]);
    p[7] = fmaf(Wfb[k], hv, p[7]);
    p[8] = fmaf(Wfb[512 + k], hv, p[8]);
    p[9] = fmaf(Wfb[1024 + k], hv, p[9]);
    p[10] = fmaf(Wfb[1536 + k], hv, p[10]);
  }
  #pragma unroll
  for (int i = 0; i < 11; ++i) {
    float v = p[i];
    #pragma unroll
    for (int m = 1; m < 64; m <<= 1) v += __shfl_xor(v, m);
    p[i] = v;
  }
  __shared__ float r4[4][11];
  if ((tid & 63) == 0) {
    int w = tid >> 6;
    #pragma unroll
    for (int i = 0; i < 11; ++i) r4[w][i] = p[i];
  }
  __syncthreads();
  if (tid == 0) {
    float s[11];
    #pragma unroll
    for (int i = 0; i < 11; ++i) s[i] = r4[0][i] + r4[1][i] + r4[2][i] + r4[3][i];
    float oqv = sigmoidf_(s[0] + boq[0]);
    float vg = softplusf(s[1] + bvg[0]);
    float ug = softplusf(s[2] + bug[0]);
    out[O1 + bf] = oqv; oqw[bf] = oqv;
    out[O2 + bf] = vg;  vgw[bf] = vg;
    out[O3 + bf] = ug;  ugw[bf] = ug;
    float run = 200.0f;
    #pragma unroll
    for (int j = 0; j < 4; ++j) {
      run += softplusf(s[3 + j] + bff[j]);
      out[O4 + (size_t)bf * 4 + j] = run; ffw[(size_t)bf * 4 + j] = run;
    }
    #pragma unroll
    for (int j = 0; j < 4; ++j) {
      float g = softplusf(s[7 + j] + bfb[j]) + 50.0f;
      out[O5 + (size_t)bf * 4 + j] = g; fbw[(size_t)bf * 4 + j] = g;
    }
  }
}

// ---------------- fused synth: excitation + formant IR + conv/OLA ----------------
// fast-math trig: __sinf/__cosf/__expf (args <= ~64 revolutions, err ~1e-4 << f16 path)
__global__ __launch_bounds__(256) void k_synth(
    const float* __restrict__ f0, const float* __restrict__ noise,
    const float* __restrict__ startw, const float* __restrict__ oqw,
    const float* __restrict__ vgw, const float* __restrict__ ugw,
    const float* __restrict__ ffw, const float* __restrict__ fbw,
    float* __restrict__ audio)
{
  __shared__ float es[256];
  __shared__ float fp[1536];
  __shared__ float ffs[4], fbs[4], ssc[1], wmax[4];
  int bf = blockIdx.x, tid = threadIdx.x;
  int b = bf >> 11, f = bf & 2047;

  // excitation -> es
  {
    float st = startw[bf], f0v = f0[bf], oqv = oqw[bf], vg = vgw[bf], ug = ugw[bf];
    float total = st + f0v * ((float)tid * (1.0f / 24000.0f));
    float phi = total - floorf(total);
    float peak = oqv * 0.66f;
    float rise = 0.5f * (1.0f - __cosf(PI_F * phi / (peak + 1e-6f)));
    float fall = __cosf(PI_F * (phi - peak) / (2.0f * (oqv - peak) + 1e-6f));
    float v = (phi < peak) ? rise : ((phi < oqv) ? fall : 0.0f);
    es[tid] = v * vg + noise[(size_t)bf * 256 + tid] * ug;
  }
  if (tid < 4) { ffs[tid] = ffw[(size_t)bf * 4 + tid]; fbs[tid] = fbw[(size_t)bf * 4 + tid]; }
  fp[tid] = 0.0f;          // fp[0..255]
  fp[1280 + tid] = 0.0f;   // fp[1280..1535]
  __syncthreads();

  // formant IR + normalization -> fp[256..1279] reversed
  float vals[4];
  float am = 0.f;
  #pragma unroll
  for (int it = 0; it < 4; ++it) {
    int k = it * 256 + tid;
    float t = (float)k * (1.0f / 24000.0f);
    float s = 0.f;
    #pragma unroll
    for (int j = 0; j < 4; ++j)
      s += __expf(-PI_F * fbs[j] * t) * __sinf(TWO_PI_F * ffs[j] * t);
    vals[it] = s;
    am = fmaxf(am, fabsf(s));
  }
  #pragma unroll
  for (int m = 1; m < 64; m <<= 1) am = fmaxf(am, __shfl_xor(am, m));
  if ((tid & 63) == 0) wmax[tid >> 6] = am;
  __syncthreads();
  if (tid == 0) ssc[0] = fmaxf(fmaxf(wmax[0], wmax[1]), fmaxf(wmax[2], wmax[3])) + 1e-8f;
  __syncthreads();
  float inv = 1.0f / ssc[0];
  #pragma unroll
  for (int it = 0; it < 4; ++it) {
    int k = it * 256 + tid;
    fp[256 + (1023 - k)] = vals[it] * inv;
  }
  __syncthreads();

  // conv (full) + overlap-add
  int n0 = tid * 5;
  float V0 = fp[n0 + 256], V1 = fp[n0 + 257], V2 = fp[n0 + 258], V3 = fp[n0 + 259], V4 = fp[n0 + 260];
  float a0 = 0.f, a1 = 0.f, a2 = 0.f, a3 = 0.f, a4 = 0.f;
  #pragma unroll 4
  for (int m = 0; m < 256; ++m) {
    float e = es[m];
    a0 = fmaf(e, V0, a0); a1 = fmaf(e, V1, a1); a2 = fmaf(e, V2, a2);
    a3 = fmaf(e, V3, a3); a4 = fmaf(e, V4, a4);
    V4 = V3; V3 = V2; V2 = V1; V1 = V0;
    V0 = fp[n0 + 255 - m];
  }
  float* arow = audio + (size_t)b * AROW + APAD + (size_t)f * 256;
  if (n0 + 0 < LL) atomicAdd(&arow[n0 + 0], a0);
  if (n0 + 1 < LL) atomicAdd(&arow[n0 + 1], a1);
  if (n0 + 2 < LL) atomicAdd(&arow[n0 + 2], a2);
  if (n0 + 3 < LL) atomicAdd(&arow[n0 + 3], a3);
  if (n0 + 4 < LL) atomicAdd(&arow[n0 + 4], a4);
}

// ---------------- pack audio fp32 -> f16 halves (row stride AROW2, zero tail pad) ----------------
__global__ __launch_bounds__(256) void k_packaudio(const float* __restrict__ audio,
                                                   unsigned* __restrict__ af) {
  int idx = blockIdx.x * 256 + threadIdx.x;   // dword index (2 halves)
  int b = blockIdx.y;
  size_t i0 = (size_t)idx * 2;
  if (i0 < AROW2) {
    float a = (i0 < AROW)     ? audio[(size_t)b * AROW + i0]     : 0.0f;
    float c = (i0 + 1 < AROW) ? audio[(size_t)b * AROW + i0 + 1] : 0.0f;
    union { unsigned u32; _Float16 h[2]; } pk;
    pk.h[0] = (_Float16)a; pk.h[1] = (_Float16)c;
    af[(size_t)b * (AROW2 / 2) + idx] = pk.u32;
  }
}

// ---------------- reverb v6: block-Toeplitz MFMA conv ----------------
constexpr int PC = 16;       // tap-pairs per chunk
constexpr int NCHUNK = 47;   // covers p 0..751 (752 padded with zeros)
constexpr int WINH = 2544;   // window halves: 32*(PC-1) + 2064

__global__ __launch_bounds__(256) void k_reverb(
    const float* __restrict__ audio, const unsigned short* __restrict__ af,
    const uint4* __restrict__ wtap, const float* __restrict__ wetl,
    float* __restrict__ out)
{
  __shared__ __align__(16) unsigned short win[WINH];
  __shared__ uint4 wlds[PC * 64];
  int tb = blockIdx.x, b = blockIdx.y, tid = threadIdx.x;
  const int wv = tid >> 6, lane = tid & 63;
  const int lm = lane & 15, quad = lane >> 4;
  int q0 = tb * 128;
  const unsigned short* afrow = af + (size_t)b * AROW2;
  f32x4 acc0 = {0.f,0.f,0.f,0.f}, acc1 = {0.f,0.f,0.f,0.f};

  for (int c = 0; c < NCHUNK; ++c) {
    int p0 = c * PC;
    int b_lo = 16 * q0 - 32 * (p0 + PC - 1) - 16;        // >= -24048; APAD covers it
    const uint4* src = (const uint4*)(afrow + (APAD + b_lo));
    __syncthreads();
    for (int u = tid; u < 318 + PC * 64; u += 256) {
      if (u < 318) ((uint4*)win)[u] = src[u];
      else         wlds[u - 318] = wtap[(size_t)p0 * 64 + (u - 318)];
    }
    __syncthreads();
    int offb = 16 * lm + 8 * quad;
    int tA = (2 * wv) * 256 + offb, tB = (2 * wv + 1) * 256 + offb;
    #pragma unroll 4
    for (int pl = 0; pl < PC; ++pl) {
      union { uint4 u; f16x8 h; } wf, b0, b1;
      wf.u = wlds[pl * 64 + lane];
      int offp = 32 * (PC - 1 - pl);
      b0.u = *(const uint4*)&win[offp + tA];
      b1.u = *(const uint4*)&win[offp + tB];
      acc0 = __builtin_amdgcn_mfma_f32_16x16x32_f16(wf.h, b0.h, acc0, 0, 0, 0);
      acc1 = __builtin_amdgcn_mfma_f32_16x16x32_f16(wf.h, b1.h, acc1, 0, 0, 0);
    }
  }
  float wet = sigmoidf_(wetl[0]);
  const float* arow = audio + (size_t)b * AROW;
  #pragma unroll
  for (int tile = 0; tile < 2; ++tile) {
    const f32x4& ac = tile ? acc1 : acc0;
    int qt = q0 + (2 * wv + tile) * 16 + lm;
    #pragma unroll
    for (int rg = 0; rg < 4; ++rg) {
      long t = (long)16 * qt + quad * 4 + rg;
      if (t < (long)TOT) {
        float av = arow[APAD + t];
        out[(size_t)b * TOT + t] = (1.0f - wet) * av + wet * ac[rg];
      }
    }
  }
}

// ---------------- launch ----------------
extern "C" void kernel_launch(void* const* d_in, const int* in_sizes, int n_in,
                              void* d_out, int out_size, void* d_ws, size_t ws_size,
                              hipStream_t stream) {
  const float* f0       = (const float*)d_in[0];
  const float* loud     = (const float*)d_in[1];
  const float* gender   = (const float*)d_in[2];
  const float* age      = (const float*)d_in[3];
  const float* z        = (const float*)d_in[4];
  const float* noise    = (const float*)d_in[5];
  const float* W_in     = (const float*)d_in[6];
  const float* b_in     = (const float*)d_in[7];
  const float* W_ih     = (const float*)d_in[8];
  const float* W_hh     = (const float*)d_in[9];
  const float* b_ih     = (const float*)d_in[10];
  const float* b_hh     = (const float*)d_in[11];
  const float* W_oq     = (const float*)d_in[12];
  const float* b_oq     = (const float*)d_in[13];
  const float* W_vg     = (const float*)d_in[14];
  const float* b_vg     = (const float*)d_in[15];
  const float* W_ug     = (const float*)d_in[16];
  const float* b_ug     = (const float*)d_in[17];
  const float* W_ff     = (const float*)d_in[18];
  const float* b_ff     = (const float*)d_in[19];
  const float* W_fb     = (const float*)d_in[20];
  const float* b_fb     = (const float*)d_in[21];
  const float* rev_ir   = (const float*)d_in[22];
  const float* wet_l    = (const float*)d_in[23];

  float* out = (float*)d_out;
  char* ws = (char*)d_ws;
  float* x      = (float*)(ws + OFF_X);
  float* gi     = (float*)(ws + OFF_GI);
  float* hs     = (float*)(ws + OFF_HS);
  float* oqw    = (float*)(ws + OFF_OQ);
  float* vgw    = (float*)(ws + OFF_VG);
  float* ugw    = (float*)(ws + OFF_UG);
  float* ffw    = (float*)(ws + OFF_FFW);
  float* fbw    = (float*)(ws + OFF_FBW);
  float* startw = (float*)(ws + OFF_START);
  float* f0m    = (float*)(ws + OFF_F0M);
  unsigned long long* hbuf = (unsigned long long*)(ws + OFF_HBUF);
  uint4* wtap   = (uint4*)(ws + OFF_WTAP);
  unsigned* af  = (unsigned*)(ws + OFF_AF16);
  float* audio  = (float*)(ws + OFF_AUDIO);

  // zero tagged h double-buffer (16KB, overlays ffw until k_heads) + audio acc
  hipMemsetAsync(ws + OFF_HBUF, 0, 16384, stream);
  hipMemsetAsync(ws + OFF_AUDIO, 0, (size_t)4 * AROW * 4, stream);

  k_f0mean<<<4, 256, 0, stream>>>(f0, f0m);
  k_inproj<<<512, 256, 0, stream>>>(f0, loud, gender, age, z, f0m, W_in, b_in, x);
  k_gemm_gi<<<dim3(24, 128), 256, 0, stream>>>(x, W_ih, b_ih, gi);
  k_gru<<<256, 256, 0, stream>>>(W_hh, b_hh, gi, hs, hbuf,
                                 f0, startw, rev_ir, wtap);   // +scan & wtaps on idle CUs
  k_heads<<<8192, 256, 0, stream>>>(hs, W_oq, b_oq, W_vg, b_vg, W_ug, b_ug,
                                    W_ff, b_ff, W_fb, b_fb, out, oqw, vgw, ugw, ffw, fbw);
  k_synth<<<8192, 256, 0, stream>>>(f0, noise, startw, oqw, vgw, ugw, ffw, fbw, audio);
  k_packaudio<<<dim3(1077, 4), 256, 0, stream>>>(audio, af);  // x region dead after gemm
  k_reverb<<<dim3(257, 4), 256, 0, stream>>>(audio, (const unsigned short*)af, wtap, wet_l, out);
}